// Round 9
// baseline (295.832 us; speedup 1.0000x reference)
//
#include <hip/hip_runtime.h>
#include <hip/hip_bf16.h>

// Problem constants (HyperGCNConv: N=100000, M=50000, K=8, DIN=DOUT=128)
#define NV 100000
#define ME 50000
#define NINC (ME * 8)                     // 400000 incidences
#define NBLK ((NV + 255) / 256)           // 391 scan blocks
#define NRBG ((NV + 127) / 128)           // 782 gemm row-blocks (128 rows each)
constexpr float WMED = 1.0f / 13.0f;      // 1/(2K-3), K=8

typedef __attribute__((ext_vector_type(8))) short bf16x8;   // MFMA A/B frag
typedef __attribute__((ext_vector_type(4))) float f32x4;    // MFMA C/D frag

static __device__ inline void cvt_split8(const float4& a, const float4& b,
                                         bf16x8& hi, bf16x8& lo) {
    const float v[8] = {a.x, a.y, a.z, a.w, b.x, b.y, b.z, b.w};
    #pragma unroll
    for (int j = 0; j < 8; ++j) {
        __hip_bfloat16 h = __float2bfloat16(v[j]);
        const float hf = __bfloat162float(h);
        __hip_bfloat16 l = __float2bfloat16(v[j] - hf);
        union { __hip_bfloat16 b; short s; } uh{h}, ul{l};
        hi[j] = uh.s;
        lo[j] = ul.s;
    }
}

// ---------------- K0: one-off W split into frag-layout global buffer -------
// Wg frag index = mat*2048 + cb*1024 + (s*4+gp)*64 + (qq*16 + m); 16B frags.
__global__ __launch_bounds__(256) void k_wsplit(const float* __restrict__ W,
                                                short* __restrict__ Wg) {
    const int idx = blockIdx.x * 256 + threadIdx.x;   // 16384 elems
    const int k = idx >> 7;          // row 0..127
    const int c = idx & 127;         // col 0..127
    const float w = W[idx];
    __hip_bfloat16 h = __float2bfloat16(w);
    const float hf = __bfloat162float(h);
    __hip_bfloat16 l = __float2bfloat16(w - hf);
    const int cb = c >> 6, gp = (c >> 4) & 3, m = c & 15;
    const int s = k >> 5, qq = (k >> 3) & 3, j = k & 7;
    const int base = cb * 1024 + (s * 4 + gp) * 64 + qq * 16 + m;
    union { __hip_bfloat16 b; short s; } uh{h}, ul{l};
    Wg[(long)base * 8 + j] = uh.s;                    // mat 0 (Wh)
    Wg[(long)(2048 + base) * 8 + j] = ul.s;           // mat 1 (Wl)
}

// ---------------- K1: Y = X @ W + b via split-bf16 MFMA ----------------
// R6: LDS-FREE. Wg (64KB) stays hot in each XCD's L2; B-frags are read
// directly (16B/lane coalesced, L2 latency hidden under MFMAs). No staging,
// no barrier -> waves fully async. 2-stage A prefetch. g-innermost epilogue.
// (R6 verified: left top-5, faster than the 44.2us LDS version.)
__global__ __launch_bounds__(256, 4) void k_gemm(const float* __restrict__ X,
                                                 const uint4* __restrict__ Wg,
                                                 const float* __restrict__ bias,
                                                 float* __restrict__ Y,
                                                 __hip_bfloat16* __restrict__ Ybf) {
    const int t = threadIdx.x;
    const int wv = t >> 6;         // wave 0..3 -> rows 32wv..32wv+31
    const int L  = t & 63;
    const int m  = L & 15;         // A row sel / B,C col sel
    const int q  = L >> 4;         // k-quad / C row-quad

    const int rb = blockIdx.x >> 1;       // row block (128 rows)
    const int cb = blockIdx.x & 1;        // col block (64 cols)

    const int row_base = rb * 128 + wv * 32;
    int r0 = row_base + m;      if (r0 > NV - 1) r0 = NV - 1;
    int r1 = row_base + 16 + m; if (r1 > NV - 1) r1 = NV - 1;
    const float* p0 = X + (long)r0 * 128 + q * 8;
    const float* p1 = X + (long)r1 * 128 + q * 8;

    const bf16x8* Whf = (const bf16x8*)Wg + cb * 1024;          // hi frags
    const bf16x8* Wlf = (const bf16x8*)Wg + 2048 + cb * 1024;   // lo frags

    f32x4 acc[2][4];
    #pragma unroll
    for (int tt = 0; tt < 2; ++tt)
        #pragma unroll
        for (int g = 0; g < 4; ++g)
            acc[tt][g] = (f32x4){0.f, 0.f, 0.f, 0.f};

    // 2-stage A pipeline: prefetch s+1 while computing s
    float4 Ac0 = *(const float4*)(p0);
    float4 Ac1 = *(const float4*)(p0 + 4);
    float4 Ac2 = *(const float4*)(p1);
    float4 Ac3 = *(const float4*)(p1 + 4);

    #pragma unroll
    for (int s = 0; s < 4; ++s) {
        float4 An0, An1, An2, An3;
        if (s < 3) {
            An0 = *(const float4*)(p0 + (s + 1) * 32);
            An1 = *(const float4*)(p0 + (s + 1) * 32 + 4);
            An2 = *(const float4*)(p1 + (s + 1) * 32);
            An3 = *(const float4*)(p1 + (s + 1) * 32 + 4);
        }
        bf16x8 ah0, al0, ah1, al1;
        cvt_split8(Ac0, Ac1, ah0, al0);
        cvt_split8(Ac2, Ac3, ah1, al1);
        #pragma unroll
        for (int g = 0; g < 4; ++g) {
            const bf16x8 bh = Whf[(s * 4 + g) * 64 + L];
            const bf16x8 bl = Wlf[(s * 4 + g) * 64 + L];
            acc[0][g] = __builtin_amdgcn_mfma_f32_16x16x32_bf16(ah0, bh, acc[0][g], 0, 0, 0);
            acc[0][g] = __builtin_amdgcn_mfma_f32_16x16x32_bf16(ah0, bl, acc[0][g], 0, 0, 0);
            acc[0][g] = __builtin_amdgcn_mfma_f32_16x16x32_bf16(al0, bh, acc[0][g], 0, 0, 0);
            acc[1][g] = __builtin_amdgcn_mfma_f32_16x16x32_bf16(ah1, bh, acc[1][g], 0, 0, 0);
            acc[1][g] = __builtin_amdgcn_mfma_f32_16x16x32_bf16(ah1, bl, acc[1][g], 0, 0, 0);
            acc[1][g] = __builtin_amdgcn_mfma_f32_16x16x32_bf16(al1, bh, acc[1][g], 0, 0, 0);
        }
        if (s < 3) { Ac0 = An0; Ac1 = An1; Ac2 = An2; Ac3 = An3; }
    }

    // bias per col-group, hoisted
    float bc[4];
    #pragma unroll
    for (int g = 0; g < 4; ++g) bc[g] = bias[cb * 64 + g * 16 + m];

    // epilogue: C layout col=lane&15, row=quad*4+reg; g INNERMOST
    #pragma unroll
    for (int tt = 0; tt < 2; ++tt) {
        #pragma unroll
        for (int r = 0; r < 4; ++r) {
            const int row = row_base + tt * 16 + q * 4 + r;
            float vg[4], vn[4];
            #pragma unroll
            for (int g = 0; g < 4; ++g) {
                vg[g] = acc[tt][g][r] + bc[g];
                vn[g] = __shfl_xor(vg[g], 1);   // neighbor col (lane pair)
            }
            if (row < NV) {
                #pragma unroll
                for (int g = 0; g < 4; ++g)
                    Y[(long)row * 128 + cb * 64 + g * 16 + m] = vg[g];
                if ((L & 1) == 0) {
                    #pragma unroll
                    for (int g = 0; g < 4; ++g) {
                        __hip_bfloat162 h2;
                        h2.x = __float2bfloat16(vg[g]);
                        h2.y = __float2bfloat16(vn[g]);
                        *(__hip_bfloat162*)(Ybf + (long)row * 128 + cb * 64 + g * 16 + m) = h2;
                    }
                }
            }
        }
    }
}

// ---------------- K2: per-hyperedge argmax pair (uvpos only) ----------------
// R9: revert to the R2 structure (best measured: 42.6us; dim-split 43.7,
// MFMA-Gram 54.4 both regressed -- the kernel is random-row-gather bound,
// FETCH 93MB at ~2TB/s effective, and the R2 schedule handles it best).
// One evidence-backed fix kept: the 128-deep serial fmaf chain (VALUBusy
// only 44% in R2) is split into 4 independent accumulators.
__global__ __launch_bounds__(256) void k_edge(const float* __restrict__ Y,
                                              const int* __restrict__ vertex,
                                              int* __restrict__ uvpos) {
    __shared__ float sF[4][8 * 132];
    const int wid = threadIdx.x >> 6;
    const int lane = threadIdx.x & 63;
    const int m = blockIdx.x * 4 + wid;
    float* F = sF[wid];

    int verts[8];
    #pragma unroll
    for (int p = 0; p < 8; ++p) verts[p] = vertex[m * 8 + p];

    #pragma unroll
    for (int p = 0; p < 8; ++p) {
        const float2 v = *(const float2*)(Y + (long)verts[p] * 128 + lane * 2);
        *(float2*)(F + p * 132 + lane * 2) = v;
    }
    __syncthreads();

    const int k = lane >> 3, l = lane & 7;
    float a0 = 0.f, a1 = 0.f, a2 = 0.f, a3 = 0.f;   // 4-way chain split
    const float4* ra = (const float4*)(F + k * 132);
    const float4* rb = (const float4*)(F + l * 132);
    #pragma unroll
    for (int d4 = 0; d4 < 32; d4 += 4) {
        const float4 x0 = ra[d4],     y0 = rb[d4];
        const float4 x1 = ra[d4 + 1], y1 = rb[d4 + 1];
        const float4 x2 = ra[d4 + 2], y2 = rb[d4 + 2];
        const float4 x3 = ra[d4 + 3], y3 = rb[d4 + 3];
        a0 = fmaf(x0.x, y0.x, a0); a0 = fmaf(x0.y, y0.y, a0);
        a0 = fmaf(x0.z, y0.z, a0); a0 = fmaf(x0.w, y0.w, a0);
        a1 = fmaf(x1.x, y1.x, a1); a1 = fmaf(x1.y, y1.y, a1);
        a1 = fmaf(x1.z, y1.z, a1); a1 = fmaf(x1.w, y1.w, a1);
        a2 = fmaf(x2.x, y2.x, a2); a2 = fmaf(x2.y, y2.y, a2);
        a2 = fmaf(x2.z, y2.z, a2); a2 = fmaf(x2.w, y2.w, a2);
        a3 = fmaf(x3.x, y3.x, a3); a3 = fmaf(x3.y, y3.y, a3);
        a3 = fmaf(x3.z, y3.z, a3); a3 = fmaf(x3.w, y3.w, a3);
    }
    const float acc = (a0 + a1) + (a2 + a3);

    const float sqk = __shfl(acc, k * 9);
    const float sql = __shfl(acc, l * 9);
    float v = sqk + sql - 2.0f * acc;
    int idx = lane;
    #pragma unroll
    for (int off = 32; off >= 1; off >>= 1) {
        const float ov = __shfl_xor(v, off);
        const int oi = __shfl_xor(idx, off);
        if (ov > v || (ov == v && oi < idx)) { v = ov; idx = oi; }
    }
    if (lane == 0) uvpos[m] = idx;
}

// ---------------- K2a: init cnt=0, deg=1, rowptr[NV]=NINC ----------------
__global__ __launch_bounds__(256) void k_init(int* __restrict__ cnt,
                                              float* __restrict__ deg,
                                              int* __restrict__ rowptr) {
    const int i = blockIdx.x * 256 + threadIdx.x;
    if (i < NV) { cnt[i] = 0; deg[i] = 1.0f; }
    if (i == 0) rowptr[NV] = NINC;
}

// ---------------- CSR build: histogram ----------------
__global__ __launch_bounds__(256) void k_hist(const int* __restrict__ vertex,
                                              int* __restrict__ cnt) {
    const int j = blockIdx.x * 256 + threadIdx.x;
    if (j < NINC) atomicAdd(cnt + vertex[j], 1);
}

// ---------------- CSR build: scan stage 1 (per-block sums) ----------------
__global__ __launch_bounds__(256) void k_scan1(const int* __restrict__ cnt,
                                               int* __restrict__ bsum) {
    __shared__ int s[256];
    const int t = threadIdx.x;
    const int i = blockIdx.x * 256 + t;
    s[t] = (i < NV) ? cnt[i] : 0;
    __syncthreads();
    #pragma unroll
    for (int off = 128; off >= 1; off >>= 1) {
        if (t < off) s[t] += s[t + off];
        __syncthreads();
    }
    if (t == 0) bsum[blockIdx.x] = s[0];
}

// ---------------- CSR build: scan stage 2 (exclusive scan of block sums) ---
__global__ __launch_bounds__(64) void k_scan2(const int* __restrict__ bsum,
                                              int* __restrict__ boff) {
    const int lane = threadIdx.x;   // single wave
    int running = 0;
    for (int c = 0; c * 64 < NBLK; ++c) {
        const int idx = c * 64 + lane;
        int v = (idx < NBLK) ? bsum[idx] : 0;
        int x = v;
        #pragma unroll
        for (int off = 1; off < 64; off <<= 1) {
            const int n = __shfl_up(x, off);
            if (lane >= off) x += n;
        }
        if (idx < NBLK) boff[idx] = running + x - v;   // exclusive
        running += __shfl(x, 63);
    }
}

// ---------------- CSR build: scan stage 3 (rowptr + fill ptr) ----------------
__global__ __launch_bounds__(256) void k_scan3(const int* __restrict__ cnt,
                                               const int* __restrict__ boff,
                                               int* __restrict__ rowptr,
                                               int* __restrict__ fill) {
    __shared__ int s[256];
    const int t = threadIdx.x;
    const int i = blockIdx.x * 256 + t;
    const int v = (i < NV) ? cnt[i] : 0;
    s[t] = v;
    __syncthreads();
    #pragma unroll
    for (int off = 1; off < 256; off <<= 1) {
        const int add = (t >= off) ? s[t - off] : 0;
        __syncthreads();
        s[t] += add;
        __syncthreads();
    }
    if (i < NV) {
        const int excl = boff[blockIdx.x] + s[t] - v;
        rowptr[i] = excl;
        fill[i] = excl;
    }
}

// ---------------- CSR build: fill entries + fused degree accumulation ------
// R9: k_deg folded in. Each incidence contributes (role? 2w : 7w) to its
// vertex's degree -- one float atomicAdd rides the existing atomic pass.
// deg initialized to 1.0 (self-loop) in k_init.
__global__ __launch_bounds__(256) void k_fill(const int* __restrict__ vertex,
                                              const int* __restrict__ uvpos,
                                              int* __restrict__ fill,
                                              int* __restrict__ entries,
                                              float* __restrict__ deg) {
    const int j = blockIdx.x * 256 + threadIdx.x;
    if (j < NINC) {
        const int v = vertex[j];
        const int m = j >> 3, p = j & 7;
        const int idx = uvpos[m];
        const int role = (p == (idx >> 3) || p == (idx & 7)) ? 0 : 1;
        const int slot = atomicAdd(fill + v, 1);
        entries[slot] = (m << 1) | role;
        atomicAdd(deg + v, role ? (2.0f * WMED) : (7.0f * WMED));
    }
}

// ---------------- K4: per-edge w*S, w*P rows (reads bf16 Y copy) ----------
__global__ __launch_bounds__(256) void k_sp(const __hip_bfloat16* __restrict__ Ybf,
                                            const int* __restrict__ vertex,
                                            const int* __restrict__ uvpos,
                                            const float* __restrict__ deg,
                                            __hip_bfloat162* __restrict__ SP) {
    const int wid = threadIdx.x >> 6;
    const int lane = threadIdx.x & 63;
    const int m = blockIdx.x * 4 + wid;

    const int idx = uvpos[m];
    const int ui = idx >> 3, vi = idx & 7;

    float S0 = 0.f, S1 = 0.f, U0 = 0.f, U1 = 0.f, V0 = 0.f, V1 = 0.f;
    #pragma unroll
    for (int p = 0; p < 8; ++p) {
        const int vp = vertex[m * 8 + p];
        const float di = rsqrtf(deg[vp]);
        const __hip_bfloat162 y2 =
            ((const __hip_bfloat162*)(Ybf + (long)vp * 128))[lane];
        const float r0 = __bfloat162float(y2.x) * di;
        const float r1 = __bfloat162float(y2.y) * di;
        S0 += r0; S1 += r1;
        if (p == ui) { U0 = r0; U1 = r1; }
        if (p == vi) { V0 = r0; V1 = r1; }
    }
    __hip_bfloat162 s2, p2;
    s2.x = __float2bfloat16(WMED * S0);
    s2.y = __float2bfloat16(WMED * S1);
    p2.x = __float2bfloat16(WMED * (U0 + V0));
    p2.y = __float2bfloat16(WMED * (U1 + V1));
    SP[(long)(2 * m) * 64 + lane] = s2;        // S row
    SP[(long)(2 * m + 1) * 64 + lane] = p2;    // P row
}

// ---------------- K5: per-vertex gather: one bf16 row per incidence --------
__global__ __launch_bounds__(256) void k_gather(const float* __restrict__ Y,
                                                const float* __restrict__ deg,
                                                const int* __restrict__ rowptr,
                                                const int* __restrict__ entries,
                                                const __hip_bfloat162* __restrict__ SP,
                                                float* __restrict__ out) {
    const int wid = threadIdx.x >> 6;
    const int lane = threadIdx.x & 63;
    const int i = blockIdx.x * 4 + wid;

    const int start = rowptr[i], end = rowptr[i + 1];
    const int degc = end - start;
    // one coalesced load grabs all entries of this row
    const int tl = (lane < degc) ? entries[start + lane] : 0;

    const float din = rsqrtf(deg[i]);
    const float2 y = *(const float2*)(Y + (long)i * 128 + lane * 2);
    const float xs0 = y.x * din;
    const float xs1 = y.y * din;

    float a0 = 0.f, a1 = 0.f;
    float fnuv = 0.f;
    const int dmain = (degc < 64) ? degc : 64;

    for (int e = 0; e < dmain; e += 4) {
        const int j1 = (e + 1 < dmain) ? e + 1 : e;
        const int j2 = (e + 2 < dmain) ? e + 2 : e;
        const int j3 = (e + 3 < dmain) ? e + 3 : e;
        const float m1 = (e + 1 < dmain) ? 1.f : 0.f;
        const float m2 = (e + 2 < dmain) ? 1.f : 0.f;
        const float m3 = (e + 3 < dmain) ? 1.f : 0.f;
        const int t0 = __shfl(tl, e);
        const int t1 = __shfl(tl, j1);
        const int t2 = __shfl(tl, j2);
        const int t3 = __shfl(tl, j3);
        // 4 independent 256B row loads issue back-to-back
        const __hip_bfloat162 T0 = SP[(long)t0 * 64 + lane];
        const __hip_bfloat162 T1 = SP[(long)t1 * 64 + lane];
        const __hip_bfloat162 T2 = SP[(long)t2 * 64 + lane];
        const __hip_bfloat162 T3 = SP[(long)t3 * 64 + lane];
        fnuv += (float)((t0 & 1) ^ 1) + m1 * (float)((t1 & 1) ^ 1)
              + m2 * (float)((t2 & 1) ^ 1) + m3 * (float)((t3 & 1) ^ 1);
        a0 += __bfloat162float(T0.x) + m1 * __bfloat162float(T1.x)
            + m2 * __bfloat162float(T2.x) + m3 * __bfloat162float(T3.x);
        a1 += __bfloat162float(T0.y) + m1 * __bfloat162float(T1.y)
            + m2 * __bfloat162float(T2.y) + m3 * __bfloat162float(T3.y);
    }
    // pathological overflow (deg > 64): serial fallback, essentially never taken
    for (int e2 = start + 64; e2 < end; ++e2) {
        const int t = entries[e2];
        const __hip_bfloat162 T = SP[(long)t * 64 + lane];
        fnuv += (float)((t & 1) ^ 1);
        a0 += __bfloat162float(T.x);
        a1 += __bfloat162float(T.y);
    }

    const float self = 1.0f - WMED * fnuv;
    a0 = fmaf(self, xs0, a0);
    a1 = fmaf(self, xs1, a1);
    float2 o;
    o.x = fmaxf(a0 * din, 0.0f);
    o.y = fmaxf(a1 * din, 0.0f);
    *(float2*)(out + (long)i * 128 + lane * 2) = o;
}

extern "C" void kernel_launch(void* const* d_in, const int* in_sizes, int n_in,
                              void* d_out, int out_size, void* d_ws, size_t ws_size,
                              hipStream_t stream) {
    const float* X      = (const float*)d_in[0];   // [N,128]
    const int*   vertex = (const int*)d_in[1];     // [M*8]
    // d_in[2] = edges (repeat(arange(M),8)) -- unused
    const float* W      = (const float*)d_in[3];   // [128,128]
    const float* bias   = (const float*)d_in[4];   // [128]
    float* out = (float*)d_out;                    // [N,128]

    // workspace: Y[N*128] f32 | Ybf[N*128] bf16 | SP[2M*128] bf16 | deg[N] |
    //            uvpos[M] | cnt[N] | rowptr[N+1] | fill[N] | bsum | boff |
    //            entries | Wg (pre-split W frags, 64 KB, 16B-aligned)
    float* Y              = (float*)d_ws;
    __hip_bfloat16* Ybf   = (__hip_bfloat16*)(Y + (long)NV * 128);
    __hip_bfloat162* SP   = (__hip_bfloat162*)(Ybf + (long)NV * 128);
    float* deg            = (float*)((__hip_bfloat16*)SP + (long)2 * ME * 128);
    int*   uvpos          = (int*)(deg + NV);
    int*   cnt            = uvpos + ME;
    int*   rowptr         = cnt + NV;
    int*   fill           = rowptr + NV + 1;
    int*   bsum           = fill + NV;
    int*   boff           = bsum + NBLK;
    int*   entries        = boff + NBLK;
    char*  pW             = (char*)(entries + NINC);
    uint4* Wg             = (uint4*)(((uintptr_t)pW + 15) & ~(uintptr_t)15);

    k_wsplit<<<64, 256, 0, stream>>>(W, (short*)Wg);
    k_gemm <<<NRBG * 2, 256, 0, stream>>>(X, Wg, bias, Y, Ybf);
    k_edge <<<ME / 4, 256, 0, stream>>>(Y, vertex, uvpos);
    k_init <<<NBLK, 256, 0, stream>>>(cnt, deg, rowptr);
    k_hist <<<(NINC + 255) / 256, 256, 0, stream>>>(vertex, cnt);
    k_scan1<<<NBLK, 256, 0, stream>>>(cnt, bsum);
    k_scan2<<<1, 64, 0, stream>>>(bsum, boff);
    k_scan3<<<NBLK, 256, 0, stream>>>(cnt, boff, rowptr, fill);
    k_fill <<<(NINC + 255) / 256, 256, 0, stream>>>(vertex, uvpos, fill, entries, deg);
    k_sp   <<<ME / 4, 256, 0, stream>>>(Ybf, vertex, uvpos, deg, SP);
    k_gather<<<NV / 4, 256, 0, stream>>>(Y, deg, rowptr, entries, SP, out);
}

// Round 10
// 271.866 us; speedup vs baseline: 1.0882x; 1.0882x over previous
//
#include <hip/hip_runtime.h>
#include <hip/hip_bf16.h>

// Problem constants (HyperGCNConv: N=100000, M=50000, K=8, DIN=DOUT=128)
#define NV 100000
#define ME 50000
#define NINC (ME * 8)                     // 400000 incidences
#define NBLK ((NV + 255) / 256)           // 391 scan blocks
#define NRBG ((NV + 127) / 128)           // 782 gemm row-blocks (128 rows each)
constexpr float WMED = 1.0f / 13.0f;      // 1/(2K-3), K=8

typedef __attribute__((ext_vector_type(8))) short bf16x8;   // MFMA A/B frag
typedef __attribute__((ext_vector_type(4))) float f32x4;    // MFMA C/D frag

static __device__ inline void cvt_split8(const float4& a, const float4& b,
                                         bf16x8& hi, bf16x8& lo) {
    const float v[8] = {a.x, a.y, a.z, a.w, b.x, b.y, b.z, b.w};
    #pragma unroll
    for (int j = 0; j < 8; ++j) {
        __hip_bfloat16 h = __float2bfloat16(v[j]);
        const float hf = __bfloat162float(h);
        __hip_bfloat16 l = __float2bfloat16(v[j] - hf);
        union { __hip_bfloat16 b; short s; } uh{h}, ul{l};
        hi[j] = uh.s;
        lo[j] = ul.s;
    }
}

// ---------------- K0: one-off W split into frag-layout global buffer -------
// Wg frag index = mat*2048 + cb*1024 + (s*4+gp)*64 + (qq*16 + m); 16B frags.
__global__ __launch_bounds__(256) void k_wsplit(const float* __restrict__ W,
                                                short* __restrict__ Wg) {
    const int idx = blockIdx.x * 256 + threadIdx.x;   // 16384 elems
    const int k = idx >> 7;          // row 0..127
    const int c = idx & 127;         // col 0..127
    const float w = W[idx];
    __hip_bfloat16 h = __float2bfloat16(w);
    const float hf = __bfloat162float(h);
    __hip_bfloat16 l = __float2bfloat16(w - hf);
    const int cb = c >> 6, gp = (c >> 4) & 3, m = c & 15;
    const int s = k >> 5, qq = (k >> 3) & 3, j = k & 7;
    const int base = cb * 1024 + (s * 4 + gp) * 64 + qq * 16 + m;
    union { __hip_bfloat16 b; short s; } uh{h}, ul{l};
    Wg[(long)base * 8 + j] = uh.s;                    // mat 0 (Wh)
    Wg[(long)(2048 + base) * 8 + j] = ul.s;           // mat 1 (Wl)
}

// ---------------- K1: Y = X @ W + b via split-bf16 MFMA ----------------
// R6: LDS-FREE. Wg (64KB) stays hot in each XCD's L2; B-frags are read
// directly (16B/lane coalesced, L2 latency hidden under MFMAs). No staging,
// no barrier -> waves fully async. 2-stage A prefetch. g-innermost epilogue.
__global__ __launch_bounds__(256, 4) void k_gemm(const float* __restrict__ X,
                                                 const uint4* __restrict__ Wg,
                                                 const float* __restrict__ bias,
                                                 float* __restrict__ Y,
                                                 __hip_bfloat16* __restrict__ Ybf) {
    const int t = threadIdx.x;
    const int wv = t >> 6;         // wave 0..3 -> rows 32wv..32wv+31
    const int L  = t & 63;
    const int m  = L & 15;         // A row sel / B,C col sel
    const int q  = L >> 4;         // k-quad / C row-quad

    const int rb = blockIdx.x >> 1;       // row block (128 rows)
    const int cb = blockIdx.x & 1;        // col block (64 cols)

    const int row_base = rb * 128 + wv * 32;
    int r0 = row_base + m;      if (r0 > NV - 1) r0 = NV - 1;
    int r1 = row_base + 16 + m; if (r1 > NV - 1) r1 = NV - 1;
    const float* p0 = X + (long)r0 * 128 + q * 8;
    const float* p1 = X + (long)r1 * 128 + q * 8;

    const bf16x8* Whf = (const bf16x8*)Wg + cb * 1024;          // hi frags
    const bf16x8* Wlf = (const bf16x8*)Wg + 2048 + cb * 1024;   // lo frags

    f32x4 acc[2][4];
    #pragma unroll
    for (int tt = 0; tt < 2; ++tt)
        #pragma unroll
        for (int g = 0; g < 4; ++g)
            acc[tt][g] = (f32x4){0.f, 0.f, 0.f, 0.f};

    // 2-stage A pipeline: prefetch s+1 while computing s
    float4 Ac0 = *(const float4*)(p0);
    float4 Ac1 = *(const float4*)(p0 + 4);
    float4 Ac2 = *(const float4*)(p1);
    float4 Ac3 = *(const float4*)(p1 + 4);

    #pragma unroll
    for (int s = 0; s < 4; ++s) {
        float4 An0, An1, An2, An3;
        if (s < 3) {
            An0 = *(const float4*)(p0 + (s + 1) * 32);
            An1 = *(const float4*)(p0 + (s + 1) * 32 + 4);
            An2 = *(const float4*)(p1 + (s + 1) * 32);
            An3 = *(const float4*)(p1 + (s + 1) * 32 + 4);
        }
        bf16x8 ah0, al0, ah1, al1;
        cvt_split8(Ac0, Ac1, ah0, al0);
        cvt_split8(Ac2, Ac3, ah1, al1);
        #pragma unroll
        for (int g = 0; g < 4; ++g) {
            const bf16x8 bh = Whf[(s * 4 + g) * 64 + L];
            const bf16x8 bl = Wlf[(s * 4 + g) * 64 + L];
            acc[0][g] = __builtin_amdgcn_mfma_f32_16x16x32_bf16(ah0, bh, acc[0][g], 0, 0, 0);
            acc[0][g] = __builtin_amdgcn_mfma_f32_16x16x32_bf16(ah0, bl, acc[0][g], 0, 0, 0);
            acc[0][g] = __builtin_amdgcn_mfma_f32_16x16x32_bf16(al0, bh, acc[0][g], 0, 0, 0);
            acc[1][g] = __builtin_amdgcn_mfma_f32_16x16x32_bf16(ah1, bh, acc[1][g], 0, 0, 0);
            acc[1][g] = __builtin_amdgcn_mfma_f32_16x16x32_bf16(ah1, bl, acc[1][g], 0, 0, 0);
            acc[1][g] = __builtin_amdgcn_mfma_f32_16x16x32_bf16(al1, bh, acc[1][g], 0, 0, 0);
        }
        if (s < 3) { Ac0 = An0; Ac1 = An1; Ac2 = An2; Ac3 = An3; }
    }

    // bias per col-group, hoisted
    float bc[4];
    #pragma unroll
    for (int g = 0; g < 4; ++g) bc[g] = bias[cb * 64 + g * 16 + m];

    // epilogue: C layout col=lane&15, row=quad*4+reg; g INNERMOST
    #pragma unroll
    for (int tt = 0; tt < 2; ++tt) {
        #pragma unroll
        for (int r = 0; r < 4; ++r) {
            const int row = row_base + tt * 16 + q * 4 + r;
            float vg[4], vn[4];
            #pragma unroll
            for (int g = 0; g < 4; ++g) {
                vg[g] = acc[tt][g][r] + bc[g];
                vn[g] = __shfl_xor(vg[g], 1);   // neighbor col (lane pair)
            }
            if (row < NV) {
                #pragma unroll
                for (int g = 0; g < 4; ++g)
                    Y[(long)row * 128 + cb * 64 + g * 16 + m] = vg[g];
                if ((L & 1) == 0) {
                    #pragma unroll
                    for (int g = 0; g < 4; ++g) {
                        __hip_bfloat162 h2;
                        h2.x = __float2bfloat16(vg[g]);
                        h2.y = __float2bfloat16(vn[g]);
                        *(__hip_bfloat162*)(Ybf + (long)row * 128 + cb * 64 + g * 16 + m) = h2;
                    }
                }
            }
        }
    }
}

// ---------------- K2: per-hyperedge argmax pair (uvpos only) ----------------
// R10: EXACT R2 structure (best measured 42.6us; every "improvement" since
// regressed -- the kernel is random-512B-gather bound at ~2TB/s, FETCH 93MB,
// and implementation detail is second-order). One addition: the CSR
// histogram rides along (8 lanes atomicAdd cnt under the gather latency),
// deleting the separate k_hist pass. k_init (cnt=0) now runs BEFORE this.
__global__ __launch_bounds__(256) void k_edge(const float* __restrict__ Y,
                                              const int* __restrict__ vertex,
                                              int* __restrict__ uvpos,
                                              int* __restrict__ cnt) {
    __shared__ float sF[4][8 * 132];
    const int wid = threadIdx.x >> 6;
    const int lane = threadIdx.x & 63;
    const int m = blockIdx.x * 4 + wid;
    float* F = sF[wid];

    int verts[8];
    #pragma unroll
    for (int p = 0; p < 8; ++p) verts[p] = vertex[m * 8 + p];

    // fused histogram: one atomic per incidence, hidden under the row gather
    if (lane < 8) atomicAdd(cnt + vertex[m * 8 + lane], 1);

    #pragma unroll
    for (int p = 0; p < 8; ++p) {
        const float2 v = *(const float2*)(Y + (long)verts[p] * 128 + lane * 2);
        *(float2*)(F + p * 132 + lane * 2) = v;
    }
    __syncthreads();

    const int k = lane >> 3, l = lane & 7;
    float acc = 0.0f;
    const float4* ra = (const float4*)(F + k * 132);
    const float4* rb = (const float4*)(F + l * 132);
    #pragma unroll
    for (int d4 = 0; d4 < 32; ++d4) {
        const float4 a = ra[d4], b = rb[d4];
        acc = fmaf(a.x, b.x, acc);
        acc = fmaf(a.y, b.y, acc);
        acc = fmaf(a.z, b.z, acc);
        acc = fmaf(a.w, b.w, acc);
    }
    const float sqk = __shfl(acc, k * 9);
    const float sql = __shfl(acc, l * 9);
    float v = sqk + sql - 2.0f * acc;
    int idx = lane;
    #pragma unroll
    for (int off = 32; off >= 1; off >>= 1) {
        const float ov = __shfl_xor(v, off);
        const int oi = __shfl_xor(idx, off);
        if (ov > v || (ov == v && oi < idx)) { v = ov; idx = oi; }
    }
    if (lane == 0) uvpos[m] = idx;
}

// ---------------- K2a: init cnt=0, deg=1, rowptr[NV]=NINC ----------------
__global__ __launch_bounds__(256) void k_init(int* __restrict__ cnt,
                                              float* __restrict__ deg,
                                              int* __restrict__ rowptr) {
    const int i = blockIdx.x * 256 + threadIdx.x;
    if (i < NV) { cnt[i] = 0; deg[i] = 1.0f; }
    if (i == 0) rowptr[NV] = NINC;
}

// ---------------- CSR build: scan stage 1 (per-block sums) ----------------
__global__ __launch_bounds__(256) void k_scan1(const int* __restrict__ cnt,
                                               int* __restrict__ bsum) {
    __shared__ int s[256];
    const int t = threadIdx.x;
    const int i = blockIdx.x * 256 + t;
    s[t] = (i < NV) ? cnt[i] : 0;
    __syncthreads();
    #pragma unroll
    for (int off = 128; off >= 1; off >>= 1) {
        if (t < off) s[t] += s[t + off];
        __syncthreads();
    }
    if (t == 0) bsum[blockIdx.x] = s[0];
}

// ---------------- CSR build: scan stage 2 (exclusive scan of block sums) ---
__global__ __launch_bounds__(64) void k_scan2(const int* __restrict__ bsum,
                                              int* __restrict__ boff) {
    const int lane = threadIdx.x;   // single wave
    int running = 0;
    for (int c = 0; c * 64 < NBLK; ++c) {
        const int idx = c * 64 + lane;
        int v = (idx < NBLK) ? bsum[idx] : 0;
        int x = v;
        #pragma unroll
        for (int off = 1; off < 64; off <<= 1) {
            const int n = __shfl_up(x, off);
            if (lane >= off) x += n;
        }
        if (idx < NBLK) boff[idx] = running + x - v;   // exclusive
        running += __shfl(x, 63);
    }
}

// ---------------- CSR build: scan stage 3 (rowptr + fill ptr) ----------------
__global__ __launch_bounds__(256) void k_scan3(const int* __restrict__ cnt,
                                               const int* __restrict__ boff,
                                               int* __restrict__ rowptr,
                                               int* __restrict__ fill) {
    __shared__ int s[256];
    const int t = threadIdx.x;
    const int i = blockIdx.x * 256 + t;
    const int v = (i < NV) ? cnt[i] : 0;
    s[t] = v;
    __syncthreads();
    #pragma unroll
    for (int off = 1; off < 256; off <<= 1) {
        const int add = (t >= off) ? s[t - off] : 0;
        __syncthreads();
        s[t] += add;
        __syncthreads();
    }
    if (i < NV) {
        const int excl = boff[blockIdx.x] + s[t] - v;
        rowptr[i] = excl;
        fill[i] = excl;
    }
}

// ---------------- CSR build: fill entries + fused degree accumulation ------
// R9: k_deg folded in. Each incidence contributes (role? 2w : 7w) to its
// vertex's degree -- one float atomicAdd rides the existing atomic pass.
// deg initialized to 1.0 (self-loop) in k_init.
__global__ __launch_bounds__(256) void k_fill(const int* __restrict__ vertex,
                                              const int* __restrict__ uvpos,
                                              int* __restrict__ fill,
                                              int* __restrict__ entries,
                                              float* __restrict__ deg) {
    const int j = blockIdx.x * 256 + threadIdx.x;
    if (j < NINC) {
        const int v = vertex[j];
        const int m = j >> 3, p = j & 7;
        const int idx = uvpos[m];
        const int role = (p == (idx >> 3) || p == (idx & 7)) ? 0 : 1;
        const int slot = atomicAdd(fill + v, 1);
        entries[slot] = (m << 1) | role;
        atomicAdd(deg + v, role ? (2.0f * WMED) : (7.0f * WMED));
    }
}

// ---------------- K4: per-edge w*S, w*P rows (reads bf16 Y copy) ----------
__global__ __launch_bounds__(256) void k_sp(const __hip_bfloat16* __restrict__ Ybf,
                                            const int* __restrict__ vertex,
                                            const int* __restrict__ uvpos,
                                            const float* __restrict__ deg,
                                            __hip_bfloat162* __restrict__ SP) {
    const int wid = threadIdx.x >> 6;
    const int lane = threadIdx.x & 63;
    const int m = blockIdx.x * 4 + wid;

    const int idx = uvpos[m];
    const int ui = idx >> 3, vi = idx & 7;

    float S0 = 0.f, S1 = 0.f, U0 = 0.f, U1 = 0.f, V0 = 0.f, V1 = 0.f;
    #pragma unroll
    for (int p = 0; p < 8; ++p) {
        const int vp = vertex[m * 8 + p];
        const float di = rsqrtf(deg[vp]);
        const __hip_bfloat162 y2 =
            ((const __hip_bfloat162*)(Ybf + (long)vp * 128))[lane];
        const float r0 = __bfloat162float(y2.x) * di;
        const float r1 = __bfloat162float(y2.y) * di;
        S0 += r0; S1 += r1;
        if (p == ui) { U0 = r0; U1 = r1; }
        if (p == vi) { V0 = r0; V1 = r1; }
    }
    __hip_bfloat162 s2, p2;
    s2.x = __float2bfloat16(WMED * S0);
    s2.y = __float2bfloat16(WMED * S1);
    p2.x = __float2bfloat16(WMED * (U0 + V0));
    p2.y = __float2bfloat16(WMED * (U1 + V1));
    SP[(long)(2 * m) * 64 + lane] = s2;        // S row
    SP[(long)(2 * m + 1) * 64 + lane] = p2;    // P row
}

// ---------------- K5: per-vertex gather: one bf16 row per incidence --------
__global__ __launch_bounds__(256) void k_gather(const float* __restrict__ Y,
                                                const float* __restrict__ deg,
                                                const int* __restrict__ rowptr,
                                                const int* __restrict__ entries,
                                                const __hip_bfloat162* __restrict__ SP,
                                                float* __restrict__ out) {
    const int wid = threadIdx.x >> 6;
    const int lane = threadIdx.x & 63;
    const int i = blockIdx.x * 4 + wid;

    const int start = rowptr[i], end = rowptr[i + 1];
    const int degc = end - start;
    // one coalesced load grabs all entries of this row
    const int tl = (lane < degc) ? entries[start + lane] : 0;

    const float din = rsqrtf(deg[i]);
    const float2 y = *(const float2*)(Y + (long)i * 128 + lane * 2);
    const float xs0 = y.x * din;
    const float xs1 = y.y * din;

    float a0 = 0.f, a1 = 0.f;
    float fnuv = 0.f;
    const int dmain = (degc < 64) ? degc : 64;

    for (int e = 0; e < dmain; e += 4) {
        const int j1 = (e + 1 < dmain) ? e + 1 : e;
        const int j2 = (e + 2 < dmain) ? e + 2 : e;
        const int j3 = (e + 3 < dmain) ? e + 3 : e;
        const float m1 = (e + 1 < dmain) ? 1.f : 0.f;
        const float m2 = (e + 2 < dmain) ? 1.f : 0.f;
        const float m3 = (e + 3 < dmain) ? 1.f : 0.f;
        const int t0 = __shfl(tl, e);
        const int t1 = __shfl(tl, j1);
        const int t2 = __shfl(tl, j2);
        const int t3 = __shfl(tl, j3);
        // 4 independent 256B row loads issue back-to-back
        const __hip_bfloat162 T0 = SP[(long)t0 * 64 + lane];
        const __hip_bfloat162 T1 = SP[(long)t1 * 64 + lane];
        const __hip_bfloat162 T2 = SP[(long)t2 * 64 + lane];
        const __hip_bfloat162 T3 = SP[(long)t3 * 64 + lane];
        fnuv += (float)((t0 & 1) ^ 1) + m1 * (float)((t1 & 1) ^ 1)
              + m2 * (float)((t2 & 1) ^ 1) + m3 * (float)((t3 & 1) ^ 1);
        a0 += __bfloat162float(T0.x) + m1 * __bfloat162float(T1.x)
            + m2 * __bfloat162float(T2.x) + m3 * __bfloat162float(T3.x);
        a1 += __bfloat162float(T0.y) + m1 * __bfloat162float(T1.y)
            + m2 * __bfloat162float(T2.y) + m3 * __bfloat162float(T3.y);
    }
    // pathological overflow (deg > 64): serial fallback, essentially never taken
    for (int e2 = start + 64; e2 < end; ++e2) {
        const int t = entries[e2];
        const __hip_bfloat162 T = SP[(long)t * 64 + lane];
        fnuv += (float)((t & 1) ^ 1);
        a0 += __bfloat162float(T.x);
        a1 += __bfloat162float(T.y);
    }

    const float self = 1.0f - WMED * fnuv;
    a0 = fmaf(self, xs0, a0);
    a1 = fmaf(self, xs1, a1);
    float2 o;
    o.x = fmaxf(a0 * din, 0.0f);
    o.y = fmaxf(a1 * din, 0.0f);
    *(float2*)(out + (long)i * 128 + lane * 2) = o;
}

extern "C" void kernel_launch(void* const* d_in, const int* in_sizes, int n_in,
                              void* d_out, int out_size, void* d_ws, size_t ws_size,
                              hipStream_t stream) {
    const float* X      = (const float*)d_in[0];   // [N,128]
    const int*   vertex = (const int*)d_in[1];     // [M*8]
    // d_in[2] = edges (repeat(arange(M),8)) -- unused
    const float* W      = (const float*)d_in[3];   // [128,128]
    const float* bias   = (const float*)d_in[4];   // [128]
    float* out = (float*)d_out;                    // [N,128]

    // workspace: Y[N*128] f32 | Ybf[N*128] bf16 | SP[2M*128] bf16 | deg[N] |
    //            uvpos[M] | cnt[N] | rowptr[N+1] | fill[N] | bsum | boff |
    //            entries | Wg (pre-split W frags, 64 KB, 16B-aligned)
    float* Y              = (float*)d_ws;
    __hip_bfloat16* Ybf   = (__hip_bfloat16*)(Y + (long)NV * 128);
    __hip_bfloat162* SP   = (__hip_bfloat162*)(Ybf + (long)NV * 128);
    float* deg            = (float*)((__hip_bfloat16*)SP + (long)2 * ME * 128);
    int*   uvpos          = (int*)(deg + NV);
    int*   cnt            = uvpos + ME;
    int*   rowptr         = cnt + NV;
    int*   fill           = rowptr + NV + 1;
    int*   bsum           = fill + NV;
    int*   boff           = bsum + NBLK;
    int*   entries        = boff + NBLK;
    char*  pW             = (char*)(entries + NINC);
    uint4* Wg             = (uint4*)(((uintptr_t)pW + 15) & ~(uintptr_t)15);

    k_wsplit<<<64, 256, 0, stream>>>(W, (short*)Wg);
    k_gemm <<<NRBG * 2, 256, 0, stream>>>(X, Wg, bias, Y, Ybf);
    k_init <<<NBLK, 256, 0, stream>>>(cnt, deg, rowptr);
    k_edge <<<ME / 4, 256, 0, stream>>>(Y, vertex, uvpos, cnt);
    k_scan1<<<NBLK, 256, 0, stream>>>(cnt, bsum);
    k_scan2<<<1, 64, 0, stream>>>(bsum, boff);
    k_scan3<<<NBLK, 256, 0, stream>>>(cnt, boff, rowptr, fill);
    k_fill <<<(NINC + 255) / 256, 256, 0, stream>>>(vertex, uvpos, fill, entries, deg);
    k_sp   <<<ME / 4, 256, 0, stream>>>(Ybf, vertex, uvpos, deg, SP);
    k_gather<<<NV / 4, 256, 0, stream>>>(Y, deg, rowptr, entries, SP, out);
}

// Round 11
// 266.775 us; speedup vs baseline: 1.1089x; 1.0191x over previous
//
#include <hip/hip_runtime.h>
#include <hip/hip_bf16.h>

// Problem constants (HyperGCNConv: N=100000, M=50000, K=8, DIN=DOUT=128)
#define NV 100000
#define ME 50000
#define NINC (ME * 8)                     // 400000 incidences
#define NBLK ((NV + 255) / 256)           // 391 scan blocks
#define NRBG ((NV + 127) / 128)           // 782 gemm row-blocks (128 rows each)
constexpr float WMED = 1.0f / 13.0f;      // 1/(2K-3), K=8

typedef __attribute__((ext_vector_type(8))) short bf16x8;   // MFMA A/B frag
typedef __attribute__((ext_vector_type(4))) float f32x4;    // MFMA C/D frag

static __device__ inline void cvt_split8(const float4& a, const float4& b,
                                         bf16x8& hi, bf16x8& lo) {
    const float v[8] = {a.x, a.y, a.z, a.w, b.x, b.y, b.z, b.w};
    #pragma unroll
    for (int j = 0; j < 8; ++j) {
        __hip_bfloat16 h = __float2bfloat16(v[j]);
        const float hf = __bfloat162float(h);
        __hip_bfloat16 l = __float2bfloat16(v[j] - hf);
        union { __hip_bfloat16 b; short s; } uh{h}, ul{l};
        hi[j] = uh.s;
        lo[j] = ul.s;
    }
}

// ---------------- K0: one-off W split + workspace init (merged R11) --------
// Wg frag index = mat*2048 + cb*1024 + (s*4+gp)*64 + (qq*16 + m); 16B frags.
// Grid NBLK: all threads init cnt/deg; first 16384 also split W.
__global__ __launch_bounds__(256) void k_winit(const float* __restrict__ W,
                                               short* __restrict__ Wg,
                                               int* __restrict__ cnt,
                                               float* __restrict__ deg,
                                               int* __restrict__ rowptr) {
    const int i = blockIdx.x * 256 + threadIdx.x;
    if (i < NV) { cnt[i] = 0; deg[i] = 1.0f; }
    if (i == 0) rowptr[NV] = NINC;
    if (i < 16384) {
        const int k = i >> 7;          // row 0..127
        const int c = i & 127;         // col 0..127
        const float w = W[i];
        __hip_bfloat16 h = __float2bfloat16(w);
        const float hf = __bfloat162float(h);
        __hip_bfloat16 l = __float2bfloat16(w - hf);
        const int cb = c >> 6, gp = (c >> 4) & 3, m = c & 15;
        const int s = k >> 5, qq = (k >> 3) & 3, j = k & 7;
        const int base = cb * 1024 + (s * 4 + gp) * 64 + qq * 16 + m;
        union { __hip_bfloat16 b; short s; } uh{h}, ul{l};
        Wg[(long)base * 8 + j] = uh.s;                    // mat 0 (Wh)
        Wg[(long)(2048 + base) * 8 + j] = ul.s;           // mat 1 (Wl)
    }
}

// ---------------- K1: Y = X @ W + b via split-bf16 MFMA ----------------
// R6: LDS-FREE. Wg (64KB) stays hot in each XCD's L2; B-frags are read
// directly (16B/lane coalesced, L2 latency hidden under MFMAs). No staging,
// no barrier -> waves fully async. 2-stage A prefetch. g-innermost epilogue.
// Plateau-verified ~44-46us across LDS/no-LDS/hoist variants; leave alone.
__global__ __launch_bounds__(256, 4) void k_gemm(const float* __restrict__ X,
                                                 const uint4* __restrict__ Wg,
                                                 const float* __restrict__ bias,
                                                 float* __restrict__ Y,
                                                 __hip_bfloat16* __restrict__ Ybf) {
    const int t = threadIdx.x;
    const int wv = t >> 6;         // wave 0..3 -> rows 32wv..32wv+31
    const int L  = t & 63;
    const int m  = L & 15;         // A row sel / B,C col sel
    const int q  = L >> 4;         // k-quad / C row-quad

    const int rb = blockIdx.x >> 1;       // row block (128 rows)
    const int cb = blockIdx.x & 1;        // col block (64 cols)

    const int row_base = rb * 128 + wv * 32;
    int r0 = row_base + m;      if (r0 > NV - 1) r0 = NV - 1;
    int r1 = row_base + 16 + m; if (r1 > NV - 1) r1 = NV - 1;
    const float* p0 = X + (long)r0 * 128 + q * 8;
    const float* p1 = X + (long)r1 * 128 + q * 8;

    const bf16x8* Whf = (const bf16x8*)Wg + cb * 1024;          // hi frags
    const bf16x8* Wlf = (const bf16x8*)Wg + 2048 + cb * 1024;   // lo frags

    f32x4 acc[2][4];
    #pragma unroll
    for (int tt = 0; tt < 2; ++tt)
        #pragma unroll
        for (int g = 0; g < 4; ++g)
            acc[tt][g] = (f32x4){0.f, 0.f, 0.f, 0.f};

    // 2-stage A pipeline: prefetch s+1 while computing s
    float4 Ac0 = *(const float4*)(p0);
    float4 Ac1 = *(const float4*)(p0 + 4);
    float4 Ac2 = *(const float4*)(p1);
    float4 Ac3 = *(const float4*)(p1 + 4);

    #pragma unroll
    for (int s = 0; s < 4; ++s) {
        float4 An0, An1, An2, An3;
        if (s < 3) {
            An0 = *(const float4*)(p0 + (s + 1) * 32);
            An1 = *(const float4*)(p0 + (s + 1) * 32 + 4);
            An2 = *(const float4*)(p1 + (s + 1) * 32);
            An3 = *(const float4*)(p1 + (s + 1) * 32 + 4);
        }
        bf16x8 ah0, al0, ah1, al1;
        cvt_split8(Ac0, Ac1, ah0, al0);
        cvt_split8(Ac2, Ac3, ah1, al1);
        #pragma unroll
        for (int g = 0; g < 4; ++g) {
            const bf16x8 bh = Whf[(s * 4 + g) * 64 + L];
            const bf16x8 bl = Wlf[(s * 4 + g) * 64 + L];
            acc[0][g] = __builtin_amdgcn_mfma_f32_16x16x32_bf16(ah0, bh, acc[0][g], 0, 0, 0);
            acc[0][g] = __builtin_amdgcn_mfma_f32_16x16x32_bf16(ah0, bl, acc[0][g], 0, 0, 0);
            acc[0][g] = __builtin_amdgcn_mfma_f32_16x16x32_bf16(al0, bh, acc[0][g], 0, 0, 0);
            acc[1][g] = __builtin_amdgcn_mfma_f32_16x16x32_bf16(ah1, bh, acc[1][g], 0, 0, 0);
            acc[1][g] = __builtin_amdgcn_mfma_f32_16x16x32_bf16(ah1, bl, acc[1][g], 0, 0, 0);
            acc[1][g] = __builtin_amdgcn_mfma_f32_16x16x32_bf16(al1, bh, acc[1][g], 0, 0, 0);
        }
        if (s < 3) { Ac0 = An0; Ac1 = An1; Ac2 = An2; Ac3 = An3; }
    }

    // bias per col-group, hoisted
    float bc[4];
    #pragma unroll
    for (int g = 0; g < 4; ++g) bc[g] = bias[cb * 64 + g * 16 + m];

    // epilogue: C layout col=lane&15, row=quad*4+reg; g INNERMOST
    #pragma unroll
    for (int tt = 0; tt < 2; ++tt) {
        #pragma unroll
        for (int r = 0; r < 4; ++r) {
            const int row = row_base + tt * 16 + q * 4 + r;
            float vg[4], vn[4];
            #pragma unroll
            for (int g = 0; g < 4; ++g) {
                vg[g] = acc[tt][g][r] + bc[g];
                vn[g] = __shfl_xor(vg[g], 1);   // neighbor col (lane pair)
            }
            if (row < NV) {
                #pragma unroll
                for (int g = 0; g < 4; ++g)
                    Y[(long)row * 128 + cb * 64 + g * 16 + m] = vg[g];
                if ((L & 1) == 0) {
                    #pragma unroll
                    for (int g = 0; g < 4; ++g) {
                        __hip_bfloat162 h2;
                        h2.x = __float2bfloat16(vg[g]);
                        h2.y = __float2bfloat16(vn[g]);
                        *(__hip_bfloat162*)(Ybf + (long)row * 128 + cb * 64 + g * 16 + m) = h2;
                    }
                }
            }
        }
    }
}

// ---------------- K2: per-hyperedge argmax pair (uvpos only) ----------------
// R10 structure kept: random-512B-gather bound (~2.2TB/s fabric, FETCH 93MB,
// floor ~42us -- implementation-insensitive, verified across 4 variants).
// Fused CSR histogram rides under the gather latency.
__global__ __launch_bounds__(256) void k_edge(const float* __restrict__ Y,
                                              const int* __restrict__ vertex,
                                              int* __restrict__ uvpos,
                                              int* __restrict__ cnt) {
    __shared__ float sF[4][8 * 132];
    const int wid = threadIdx.x >> 6;
    const int lane = threadIdx.x & 63;
    const int m = blockIdx.x * 4 + wid;
    float* F = sF[wid];

    int verts[8];
    #pragma unroll
    for (int p = 0; p < 8; ++p) verts[p] = vertex[m * 8 + p];

    // fused histogram: one atomic per incidence, hidden under the row gather
    if (lane < 8) atomicAdd(cnt + vertex[m * 8 + lane], 1);

    #pragma unroll
    for (int p = 0; p < 8; ++p) {
        const float2 v = *(const float2*)(Y + (long)verts[p] * 128 + lane * 2);
        *(float2*)(F + p * 132 + lane * 2) = v;
    }
    __syncthreads();

    const int k = lane >> 3, l = lane & 7;
    float acc = 0.0f;
    const float4* ra = (const float4*)(F + k * 132);
    const float4* rb = (const float4*)(F + l * 132);
    #pragma unroll
    for (int d4 = 0; d4 < 32; ++d4) {
        const float4 a = ra[d4], b = rb[d4];
        acc = fmaf(a.x, b.x, acc);
        acc = fmaf(a.y, b.y, acc);
        acc = fmaf(a.z, b.z, acc);
        acc = fmaf(a.w, b.w, acc);
    }
    const float sqk = __shfl(acc, k * 9);
    const float sql = __shfl(acc, l * 9);
    float v = sqk + sql - 2.0f * acc;
    int idx = lane;
    #pragma unroll
    for (int off = 32; off >= 1; off >>= 1) {
        const float ov = __shfl_xor(v, off);
        const int oi = __shfl_xor(idx, off);
        if (ov > v || (ov == v && oi < idx)) { v = ov; idx = oi; }
    }
    if (lane == 0) uvpos[m] = idx;
}

// ---------------- CSR build: scan stage 1 (per-block sums) ----------------
__global__ __launch_bounds__(256) void k_scan1(const int* __restrict__ cnt,
                                               int* __restrict__ bsum) {
    __shared__ int s[256];
    const int t = threadIdx.x;
    const int i = blockIdx.x * 256 + t;
    s[t] = (i < NV) ? cnt[i] : 0;
    __syncthreads();
    #pragma unroll
    for (int off = 128; off >= 1; off >>= 1) {
        if (t < off) s[t] += s[t + off];
        __syncthreads();
    }
    if (t == 0) bsum[blockIdx.x] = s[0];
}

// ---------------- CSR build: scan stage 2+3 merged (R11) -------------------
// Each block computes its own exclusive block-offset by wave-reducing
// bsum[0..b) directly (<=391 ints, L2-hot: ~7 coalesced reads/lane).
// Deletes the separate k_scan2 launch; rowptr/fill bitwise identical.
__global__ __launch_bounds__(256) void k_scan3(const int* __restrict__ cnt,
                                               const int* __restrict__ bsum,
                                               int* __restrict__ rowptr,
                                               int* __restrict__ fill) {
    __shared__ int s[256];
    __shared__ int base_s;
    const int t = threadIdx.x;
    const int b = blockIdx.x;
    const int i = b * 256 + t;
    const int v = (i < NV) ? cnt[i] : 0;
    s[t] = v;
    if (t < 64) {
        int sum = 0;
        for (int j = t; j < b; j += 64) sum += bsum[j];
        #pragma unroll
        for (int off = 32; off >= 1; off >>= 1) sum += __shfl_xor(sum, off);
        if (t == 0) base_s = sum;
    }
    __syncthreads();
    #pragma unroll
    for (int off = 1; off < 256; off <<= 1) {
        const int add = (t >= off) ? s[t - off] : 0;
        __syncthreads();
        s[t] += add;
        __syncthreads();
    }
    if (i < NV) {
        const int excl = base_s + s[t] - v;
        rowptr[i] = excl;
        fill[i] = excl;
    }
}

// ---------------- CSR build: fill entries + fused degree accumulation ------
// R9: k_deg folded in. Each incidence contributes (role? 2w : 7w) to its
// vertex's degree -- one float atomicAdd rides the existing atomic pass.
__global__ __launch_bounds__(256) void k_fill(const int* __restrict__ vertex,
                                              const int* __restrict__ uvpos,
                                              int* __restrict__ fill,
                                              int* __restrict__ entries,
                                              float* __restrict__ deg) {
    const int j = blockIdx.x * 256 + threadIdx.x;
    if (j < NINC) {
        const int v = vertex[j];
        const int m = j >> 3, p = j & 7;
        const int idx = uvpos[m];
        const int role = (p == (idx >> 3) || p == (idx & 7)) ? 0 : 1;
        const int slot = atomicAdd(fill + v, 1);
        entries[slot] = (m << 1) | role;
        atomicAdd(deg + v, role ? (2.0f * WMED) : (7.0f * WMED));
    }
}

// ---------------- K4: per-edge w*S, w*P rows (reads bf16 Y copy) ----------
__global__ __launch_bounds__(256) void k_sp(const __hip_bfloat16* __restrict__ Ybf,
                                            const int* __restrict__ vertex,
                                            const int* __restrict__ uvpos,
                                            const float* __restrict__ deg,
                                            __hip_bfloat162* __restrict__ SP) {
    const int wid = threadIdx.x >> 6;
    const int lane = threadIdx.x & 63;
    const int m = blockIdx.x * 4 + wid;

    const int idx = uvpos[m];
    const int ui = idx >> 3, vi = idx & 7;

    float S0 = 0.f, S1 = 0.f, U0 = 0.f, U1 = 0.f, V0 = 0.f, V1 = 0.f;
    #pragma unroll
    for (int p = 0; p < 8; ++p) {
        const int vp = vertex[m * 8 + p];
        const float di = rsqrtf(deg[vp]);
        const __hip_bfloat162 y2 =
            ((const __hip_bfloat162*)(Ybf + (long)vp * 128))[lane];
        const float r0 = __bfloat162float(y2.x) * di;
        const float r1 = __bfloat162float(y2.y) * di;
        S0 += r0; S1 += r1;
        if (p == ui) { U0 = r0; U1 = r1; }
        if (p == vi) { V0 = r0; V1 = r1; }
    }
    __hip_bfloat162 s2, p2;
    s2.x = __float2bfloat16(WMED * S0);
    s2.y = __float2bfloat16(WMED * S1);
    p2.x = __float2bfloat16(WMED * (U0 + V0));
    p2.y = __float2bfloat16(WMED * (U1 + V1));
    SP[(long)(2 * m) * 64 + lane] = s2;        // S row
    SP[(long)(2 * m + 1) * 64 + lane] = p2;    // P row
}

// ---------------- K5: per-vertex gather: one bf16 row per incidence --------
// R11: 8-wide chunks (one round covers deg<=8, ~98% of vertices; Poisson
// lambda=4). Masked duplicates re-load the same row -> L1 hits, ~free.
__global__ __launch_bounds__(256) void k_gather(const float* __restrict__ Y,
                                                const float* __restrict__ deg,
                                                const int* __restrict__ rowptr,
                                                const int* __restrict__ entries,
                                                const __hip_bfloat162* __restrict__ SP,
                                                float* __restrict__ out) {
    const int wid = threadIdx.x >> 6;
    const int lane = threadIdx.x & 63;
    const int i = blockIdx.x * 4 + wid;

    const int start = rowptr[i], end = rowptr[i + 1];
    const int degc = end - start;
    // one coalesced load grabs all entries of this row
    const int tl = (lane < degc) ? entries[start + lane] : 0;

    const float din = rsqrtf(deg[i]);
    const float2 y = *(const float2*)(Y + (long)i * 128 + lane * 2);
    const float xs0 = y.x * din;
    const float xs1 = y.y * din;

    float a0 = 0.f, a1 = 0.f;
    float fnuv = 0.f;
    const int dmain = (degc < 64) ? degc : 64;

    for (int e = 0; e < dmain; e += 8) {
        const int j1 = (e + 1 < dmain) ? e + 1 : e;
        const int j2 = (e + 2 < dmain) ? e + 2 : e;
        const int j3 = (e + 3 < dmain) ? e + 3 : e;
        const int j4 = (e + 4 < dmain) ? e + 4 : e;
        const int j5 = (e + 5 < dmain) ? e + 5 : e;
        const int j6 = (e + 6 < dmain) ? e + 6 : e;
        const int j7 = (e + 7 < dmain) ? e + 7 : e;
        const float m1 = (e + 1 < dmain) ? 1.f : 0.f;
        const float m2 = (e + 2 < dmain) ? 1.f : 0.f;
        const float m3 = (e + 3 < dmain) ? 1.f : 0.f;
        const float m4 = (e + 4 < dmain) ? 1.f : 0.f;
        const float m5 = (e + 5 < dmain) ? 1.f : 0.f;
        const float m6 = (e + 6 < dmain) ? 1.f : 0.f;
        const float m7 = (e + 7 < dmain) ? 1.f : 0.f;
        const int t0 = __shfl(tl, e);
        const int t1 = __shfl(tl, j1);
        const int t2 = __shfl(tl, j2);
        const int t3 = __shfl(tl, j3);
        const int t4 = __shfl(tl, j4);
        const int t5 = __shfl(tl, j5);
        const int t6 = __shfl(tl, j6);
        const int t7 = __shfl(tl, j7);
        // 8 independent 256B row loads issue back-to-back
        const __hip_bfloat162 T0 = SP[(long)t0 * 64 + lane];
        const __hip_bfloat162 T1 = SP[(long)t1 * 64 + lane];
        const __hip_bfloat162 T2 = SP[(long)t2 * 64 + lane];
        const __hip_bfloat162 T3 = SP[(long)t3 * 64 + lane];
        const __hip_bfloat162 T4 = SP[(long)t4 * 64 + lane];
        const __hip_bfloat162 T5 = SP[(long)t5 * 64 + lane];
        const __hip_bfloat162 T6 = SP[(long)t6 * 64 + lane];
        const __hip_bfloat162 T7 = SP[(long)t7 * 64 + lane];
        fnuv += (float)((t0 & 1) ^ 1) + m1 * (float)((t1 & 1) ^ 1)
              + m2 * (float)((t2 & 1) ^ 1) + m3 * (float)((t3 & 1) ^ 1)
              + m4 * (float)((t4 & 1) ^ 1) + m5 * (float)((t5 & 1) ^ 1)
              + m6 * (float)((t6 & 1) ^ 1) + m7 * (float)((t7 & 1) ^ 1);
        a0 += __bfloat162float(T0.x) + m1 * __bfloat162float(T1.x)
            + m2 * __bfloat162float(T2.x) + m3 * __bfloat162float(T3.x)
            + m4 * __bfloat162float(T4.x) + m5 * __bfloat162float(T5.x)
            + m6 * __bfloat162float(T6.x) + m7 * __bfloat162float(T7.x);
        a1 += __bfloat162float(T0.y) + m1 * __bfloat162float(T1.y)
            + m2 * __bfloat162float(T2.y) + m3 * __bfloat162float(T3.y)
            + m4 * __bfloat162float(T4.y) + m5 * __bfloat162float(T5.y)
            + m6 * __bfloat162float(T6.y) + m7 * __bfloat162float(T7.y);
    }
    // pathological overflow (deg > 64): serial fallback, essentially never taken
    for (int e2 = start + 64; e2 < end; ++e2) {
        const int t = entries[e2];
        const __hip_bfloat162 T = SP[(long)t * 64 + lane];
        fnuv += (float)((t & 1) ^ 1);
        a0 += __bfloat162float(T.x);
        a1 += __bfloat162float(T.y);
    }

    const float self = 1.0f - WMED * fnuv;
    a0 = fmaf(self, xs0, a0);
    a1 = fmaf(self, xs1, a1);
    float2 o;
    o.x = fmaxf(a0 * din, 0.0f);
    o.y = fmaxf(a1 * din, 0.0f);
    *(float2*)(out + (long)i * 128 + lane * 2) = o;
}

extern "C" void kernel_launch(void* const* d_in, const int* in_sizes, int n_in,
                              void* d_out, int out_size, void* d_ws, size_t ws_size,
                              hipStream_t stream) {
    const float* X      = (const float*)d_in[0];   // [N,128]
    const int*   vertex = (const int*)d_in[1];     // [M*8]
    // d_in[2] = edges (repeat(arange(M),8)) -- unused
    const float* W      = (const float*)d_in[3];   // [128,128]
    const float* bias   = (const float*)d_in[4];   // [128]
    float* out = (float*)d_out;                    // [N,128]

    // workspace: Y[N*128] f32 | Ybf[N*128] bf16 | SP[2M*128] bf16 | deg[N] |
    //            uvpos[M] | cnt[N] | rowptr[N+1] | fill[N] | bsum |
    //            entries | Wg (pre-split W frags, 64 KB, 16B-aligned)
    float* Y              = (float*)d_ws;
    __hip_bfloat16* Ybf   = (__hip_bfloat16*)(Y + (long)NV * 128);
    __hip_bfloat162* SP   = (__hip_bfloat162*)(Ybf + (long)NV * 128);
    float* deg            = (float*)((__hip_bfloat16*)SP + (long)2 * ME * 128);
    int*   uvpos          = (int*)(deg + NV);
    int*   cnt            = uvpos + ME;
    int*   rowptr         = cnt + NV;
    int*   fill           = rowptr + NV + 1;
    int*   bsum           = fill + NV;
    int*   entries        = bsum + NBLK;
    char*  pW             = (char*)(entries + NINC);
    uint4* Wg             = (uint4*)(((uintptr_t)pW + 15) & ~(uintptr_t)15);

    k_winit<<<NBLK, 256, 0, stream>>>(W, (short*)Wg, cnt, deg, rowptr);
    k_gemm <<<NRBG * 2, 256, 0, stream>>>(X, Wg, bias, Y, Ybf);
    k_edge <<<ME / 4, 256, 0, stream>>>(Y, vertex, uvpos, cnt);
    k_scan1<<<NBLK, 256, 0, stream>>>(cnt, bsum);
    k_scan3<<<NBLK, 256, 0, stream>>>(cnt, bsum, rowptr, fill);
    k_fill <<<(NINC + 255) / 256, 256, 0, stream>>>(vertex, uvpos, fill, entries, deg);
    k_sp   <<<ME / 4, 256, 0, stream>>>(Ybf, vertex, uvpos, deg, SP);
    k_gather<<<NV / 4, 256, 0, stream>>>(Y, deg, rowptr, entries, SP, out);
}

// Round 12
// 249.239 us; speedup vs baseline: 1.1869x; 1.0704x over previous
//
#include <hip/hip_runtime.h>
#include <hip/hip_bf16.h>

// Problem constants (HyperGCNConv: N=100000, M=50000, K=8, DIN=DOUT=128)
#define NV 100000
#define ME 50000
#define NINC (ME * 8)                     // 400000 incidences
#define NBLK ((NV + 255) / 256)           // 391 scan blocks
#define NRBG ((NV + 127) / 128)           // 782 gemm row-blocks (128 rows each)
constexpr float WMED = 1.0f / 13.0f;      // 1/(2K-3), K=8

typedef __attribute__((ext_vector_type(8))) short bf16x8;   // MFMA A/B frag
typedef __attribute__((ext_vector_type(4))) float f32x4;    // MFMA C/D frag

static __device__ inline void cvt_split8(const float4& a, const float4& b,
                                         bf16x8& hi, bf16x8& lo) {
    const float v[8] = {a.x, a.y, a.z, a.w, b.x, b.y, b.z, b.w};
    #pragma unroll
    for (int j = 0; j < 8; ++j) {
        __hip_bfloat16 h = __float2bfloat16(v[j]);
        const float hf = __bfloat162float(h);
        __hip_bfloat16 l = __float2bfloat16(v[j] - hf);
        union { __hip_bfloat16 b; short s; } uh{h}, ul{l};
        hi[j] = uh.s;
        lo[j] = ul.s;
    }
}

// ---------------- K0: one-off W split + workspace init (merged R11) --------
// Wg frag index = mat*2048 + cb*1024 + (s*4+gp)*64 + (qq*16 + m); 16B frags.
// Grid NBLK: all threads init cnt/deg; first 16384 also split W.
__global__ __launch_bounds__(256) void k_winit(const float* __restrict__ W,
                                               short* __restrict__ Wg,
                                               int* __restrict__ cnt,
                                               float* __restrict__ deg,
                                               int* __restrict__ gcount) {
    const int i = blockIdx.x * 256 + threadIdx.x;
    if (i < NV) { cnt[i] = 0; deg[i] = 1.0f; }
    if (i == 0) gcount[0] = 0;
    if (i < 16384) {
        const int k = i >> 7;          // row 0..127
        const int c = i & 127;         // col 0..127
        const float w = W[i];
        __hip_bfloat16 h = __float2bfloat16(w);
        const float hf = __bfloat162float(h);
        __hip_bfloat16 l = __float2bfloat16(w - hf);
        const int cb = c >> 6, gp = (c >> 4) & 3, m = c & 15;
        const int s = k >> 5, qq = (k >> 3) & 3, j = k & 7;
        const int base = cb * 1024 + (s * 4 + gp) * 64 + qq * 16 + m;
        union { __hip_bfloat16 b; short s; } uh{h}, ul{l};
        Wg[(long)base * 8 + j] = uh.s;                    // mat 0 (Wh)
        Wg[(long)(2048 + base) * 8 + j] = ul.s;           // mat 1 (Wl)
    }
}

// ---------------- K1: Y = X @ W + b via split-bf16 MFMA ----------------
// R6: LDS-FREE. Wg (64KB) stays hot in each XCD's L2; B-frags are read
// directly (16B/lane coalesced, L2 latency hidden under MFMAs). No staging,
// no barrier -> waves fully async. 2-stage A prefetch. g-innermost epilogue.
// Plateau-verified ~44-46us across LDS/no-LDS/hoist variants; leave alone.
__global__ __launch_bounds__(256, 4) void k_gemm(const float* __restrict__ X,
                                                 const uint4* __restrict__ Wg,
                                                 const float* __restrict__ bias,
                                                 float* __restrict__ Y,
                                                 __hip_bfloat16* __restrict__ Ybf) {
    const int t = threadIdx.x;
    const int wv = t >> 6;         // wave 0..3 -> rows 32wv..32wv+31
    const int L  = t & 63;
    const int m  = L & 15;         // A row sel / B,C col sel
    const int q  = L >> 4;         // k-quad / C row-quad

    const int rb = blockIdx.x >> 1;       // row block (128 rows)
    const int cb = blockIdx.x & 1;        // col block (64 cols)

    const int row_base = rb * 128 + wv * 32;
    int r0 = row_base + m;      if (r0 > NV - 1) r0 = NV - 1;
    int r1 = row_base + 16 + m; if (r1 > NV - 1) r1 = NV - 1;
    const float* p0 = X + (long)r0 * 128 + q * 8;
    const float* p1 = X + (long)r1 * 128 + q * 8;

    const bf16x8* Whf = (const bf16x8*)Wg + cb * 1024;          // hi frags
    const bf16x8* Wlf = (const bf16x8*)Wg + 2048 + cb * 1024;   // lo frags

    f32x4 acc[2][4];
    #pragma unroll
    for (int tt = 0; tt < 2; ++tt)
        #pragma unroll
        for (int g = 0; g < 4; ++g)
            acc[tt][g] = (f32x4){0.f, 0.f, 0.f, 0.f};

    // 2-stage A pipeline: prefetch s+1 while computing s
    float4 Ac0 = *(const float4*)(p0);
    float4 Ac1 = *(const float4*)(p0 + 4);
    float4 Ac2 = *(const float4*)(p1);
    float4 Ac3 = *(const float4*)(p1 + 4);

    #pragma unroll
    for (int s = 0; s < 4; ++s) {
        float4 An0, An1, An2, An3;
        if (s < 3) {
            An0 = *(const float4*)(p0 + (s + 1) * 32);
            An1 = *(const float4*)(p0 + (s + 1) * 32 + 4);
            An2 = *(const float4*)(p1 + (s + 1) * 32);
            An3 = *(const float4*)(p1 + (s + 1) * 32 + 4);
        }
        bf16x8 ah0, al0, ah1, al1;
        cvt_split8(Ac0, Ac1, ah0, al0);
        cvt_split8(Ac2, Ac3, ah1, al1);
        #pragma unroll
        for (int g = 0; g < 4; ++g) {
            const bf16x8 bh = Whf[(s * 4 + g) * 64 + L];
            const bf16x8 bl = Wlf[(s * 4 + g) * 64 + L];
            acc[0][g] = __builtin_amdgcn_mfma_f32_16x16x32_bf16(ah0, bh, acc[0][g], 0, 0, 0);
            acc[0][g] = __builtin_amdgcn_mfma_f32_16x16x32_bf16(ah0, bl, acc[0][g], 0, 0, 0);
            acc[0][g] = __builtin_amdgcn_mfma_f32_16x16x32_bf16(al0, bh, acc[0][g], 0, 0, 0);
            acc[1][g] = __builtin_amdgcn_mfma_f32_16x16x32_bf16(ah1, bh, acc[1][g], 0, 0, 0);
            acc[1][g] = __builtin_amdgcn_mfma_f32_16x16x32_bf16(ah1, bl, acc[1][g], 0, 0, 0);
            acc[1][g] = __builtin_amdgcn_mfma_f32_16x16x32_bf16(al1, bh, acc[1][g], 0, 0, 0);
        }
        if (s < 3) { Ac0 = An0; Ac1 = An1; Ac2 = An2; Ac3 = An3; }
    }

    // bias per col-group, hoisted
    float bc[4];
    #pragma unroll
    for (int g = 0; g < 4; ++g) bc[g] = bias[cb * 64 + g * 16 + m];

    // epilogue: C layout col=lane&15, row=quad*4+reg; g INNERMOST
    #pragma unroll
    for (int tt = 0; tt < 2; ++tt) {
        #pragma unroll
        for (int r = 0; r < 4; ++r) {
            const int row = row_base + tt * 16 + q * 4 + r;
            float vg[4], vn[4];
            #pragma unroll
            for (int g = 0; g < 4; ++g) {
                vg[g] = acc[tt][g][r] + bc[g];
                vn[g] = __shfl_xor(vg[g], 1);   // neighbor col (lane pair)
            }
            if (row < NV) {
                #pragma unroll
                for (int g = 0; g < 4; ++g)
                    Y[(long)row * 128 + cb * 64 + g * 16 + m] = vg[g];
                if ((L & 1) == 0) {
                    #pragma unroll
                    for (int g = 0; g < 4; ++g) {
                        __hip_bfloat162 h2;
                        h2.x = __float2bfloat16(vg[g]);
                        h2.y = __float2bfloat16(vn[g]);
                        *(__hip_bfloat162*)(Ybf + (long)row * 128 + cb * 64 + g * 16 + m) = h2;
                    }
                }
            }
        }
    }
}

// ---------------- K2: per-hyperedge argmax pair (uvpos only) ----------------
// R10 structure kept: random-512B-gather bound (~2.2TB/s fabric, FETCH 93MB,
// floor ~42us -- implementation-insensitive, verified across 4 variants).
// Fused CSR histogram rides under the gather latency (R10, ~free).
// R12: deg atomics also fused -- after the full butterfly ALL lanes hold the
// winning idx, so lanes 0..7 add their position's weight (u/v: 7w, med: 2w).
__global__ __launch_bounds__(256) void k_edge(const float* __restrict__ Y,
                                              const int* __restrict__ vertex,
                                              int* __restrict__ uvpos,
                                              int* __restrict__ cnt,
                                              float* __restrict__ deg) {
    __shared__ float sF[4][8 * 132];
    const int wid = threadIdx.x >> 6;
    const int lane = threadIdx.x & 63;
    const int m = blockIdx.x * 4 + wid;
    float* F = sF[wid];

    int verts[8];
    #pragma unroll
    for (int p = 0; p < 8; ++p) verts[p] = vertex[m * 8 + p];

    // fused histogram: one atomic per incidence, hidden under the row gather
    if (lane < 8) atomicAdd(cnt + vertex[m * 8 + lane], 1);

    #pragma unroll
    for (int p = 0; p < 8; ++p) {
        const float2 v = *(const float2*)(Y + (long)verts[p] * 128 + lane * 2);
        *(float2*)(F + p * 132 + lane * 2) = v;
    }
    __syncthreads();

    const int k = lane >> 3, l = lane & 7;
    float acc = 0.0f;
    const float4* ra = (const float4*)(F + k * 132);
    const float4* rb = (const float4*)(F + l * 132);
    #pragma unroll
    for (int d4 = 0; d4 < 32; ++d4) {
        const float4 a = ra[d4], b = rb[d4];
        acc = fmaf(a.x, b.x, acc);
        acc = fmaf(a.y, b.y, acc);
        acc = fmaf(a.z, b.z, acc);
        acc = fmaf(a.w, b.w, acc);
    }
    const float sqk = __shfl(acc, k * 9);
    const float sql = __shfl(acc, l * 9);
    float v = sqk + sql - 2.0f * acc;
    int idx = lane;
    #pragma unroll
    for (int off = 32; off >= 1; off >>= 1) {
        const float ov = __shfl_xor(v, off);
        const int oi = __shfl_xor(idx, off);
        if (ov > v || (ov == v && oi < idx)) { v = ov; idx = oi; }
    }
    if (lane == 0) uvpos[m] = idx;

    // fused degree: role by POSITION (matches ref's med mask semantics)
    if (lane < 8) {
        const int ui = idx >> 3, vi = idx & 7;
        const float w = (lane == ui || lane == vi) ? (7.0f * WMED) : (2.0f * WMED);
        atomicAdd(deg + vertex[m * 8 + lane], w);
    }
}

// ---------------- CSR build: single-pass scan (R12, merged scan1+scan3) ----
// Block-local inclusive scan; block base from an atomic global cursor.
// rowptr is no longer monotonic across blocks (arrival order), but each
// vertex's range [rowptr[i], rowptr[i]+cnt[i]) is exclusive and valid --
// k_gather uses cnt[i] for the range length.
__global__ __launch_bounds__(256) void k_scan(const int* __restrict__ cnt,
                                              int* __restrict__ gcount,
                                              int* __restrict__ rowptr,
                                              int* __restrict__ fill) {
    __shared__ int s[256];
    __shared__ int base_s;
    const int t = threadIdx.x;
    const int i = blockIdx.x * 256 + t;
    const int v = (i < NV) ? cnt[i] : 0;
    s[t] = v;
    __syncthreads();
    #pragma unroll
    for (int off = 1; off < 256; off <<= 1) {
        const int add = (t >= off) ? s[t - off] : 0;
        __syncthreads();
        s[t] += add;
        __syncthreads();
    }
    if (t == 255) base_s = atomicAdd(gcount, s[255]);
    __syncthreads();
    if (i < NV) {
        const int excl = base_s + s[t] - v;
        rowptr[i] = excl;
        fill[i] = excl;
    }
}

// ---------------- CSR build: fill entries (deg moved to k_edge, R12) -------
__global__ __launch_bounds__(256) void k_fill(const int* __restrict__ vertex,
                                              const int* __restrict__ uvpos,
                                              int* __restrict__ fill,
                                              int* __restrict__ entries) {
    const int j = blockIdx.x * 256 + threadIdx.x;
    if (j < NINC) {
        const int v = vertex[j];
        const int m = j >> 3, p = j & 7;
        const int idx = uvpos[m];
        const int role = (p == (idx >> 3) || p == (idx & 7)) ? 0 : 1;
        const int slot = atomicAdd(fill + v, 1);
        entries[slot] = (m << 1) | role;
    }
}

// ---------------- K4: per-edge w*S, w*P rows (reads bf16 Y copy) ----------
__global__ __launch_bounds__(256) void k_sp(const __hip_bfloat16* __restrict__ Ybf,
                                            const int* __restrict__ vertex,
                                            const int* __restrict__ uvpos,
                                            const float* __restrict__ deg,
                                            __hip_bfloat162* __restrict__ SP) {
    const int wid = threadIdx.x >> 6;
    const int lane = threadIdx.x & 63;
    const int m = blockIdx.x * 4 + wid;

    const int idx = uvpos[m];
    const int ui = idx >> 3, vi = idx & 7;

    float S0 = 0.f, S1 = 0.f, U0 = 0.f, U1 = 0.f, V0 = 0.f, V1 = 0.f;
    #pragma unroll
    for (int p = 0; p < 8; ++p) {
        const int vp = vertex[m * 8 + p];
        const float di = rsqrtf(deg[vp]);
        const __hip_bfloat162 y2 =
            ((const __hip_bfloat162*)(Ybf + (long)vp * 128))[lane];
        const float r0 = __bfloat162float(y2.x) * di;
        const float r1 = __bfloat162float(y2.y) * di;
        S0 += r0; S1 += r1;
        if (p == ui) { U0 = r0; U1 = r1; }
        if (p == vi) { V0 = r0; V1 = r1; }
    }
    __hip_bfloat162 s2, p2;
    s2.x = __float2bfloat16(WMED * S0);
    s2.y = __float2bfloat16(WMED * S1);
    p2.x = __float2bfloat16(WMED * (U0 + V0));
    p2.y = __float2bfloat16(WMED * (U1 + V1));
    SP[(long)(2 * m) * 64 + lane] = s2;        // S row
    SP[(long)(2 * m + 1) * 64 + lane] = p2;    // P row
}

// ---------------- K5: per-vertex gather: one bf16 row per incidence --------
// R11: 8-wide chunks (one round covers deg<=8, ~98% of vertices).
// R12: range length from cnt[i] (rowptr non-monotonic after atomic scan).
__global__ __launch_bounds__(256) void k_gather(const float* __restrict__ Y,
                                                const float* __restrict__ deg,
                                                const int* __restrict__ rowptr,
                                                const int* __restrict__ cnt,
                                                const int* __restrict__ entries,
                                                const __hip_bfloat162* __restrict__ SP,
                                                float* __restrict__ out) {
    const int wid = threadIdx.x >> 6;
    const int lane = threadIdx.x & 63;
    const int i = blockIdx.x * 4 + wid;

    const int start = rowptr[i];
    const int degc = cnt[i];
    // one coalesced load grabs all entries of this row
    const int tl = (lane < degc) ? entries[start + lane] : 0;

    const float din = rsqrtf(deg[i]);
    const float2 y = *(const float2*)(Y + (long)i * 128 + lane * 2);
    const float xs0 = y.x * din;
    const float xs1 = y.y * din;

    float a0 = 0.f, a1 = 0.f;
    float fnuv = 0.f;
    const int dmain = (degc < 64) ? degc : 64;

    for (int e = 0; e < dmain; e += 8) {
        const int j1 = (e + 1 < dmain) ? e + 1 : e;
        const int j2 = (e + 2 < dmain) ? e + 2 : e;
        const int j3 = (e + 3 < dmain) ? e + 3 : e;
        const int j4 = (e + 4 < dmain) ? e + 4 : e;
        const int j5 = (e + 5 < dmain) ? e + 5 : e;
        const int j6 = (e + 6 < dmain) ? e + 6 : e;
        const int j7 = (e + 7 < dmain) ? e + 7 : e;
        const float m1 = (e + 1 < dmain) ? 1.f : 0.f;
        const float m2 = (e + 2 < dmain) ? 1.f : 0.f;
        const float m3 = (e + 3 < dmain) ? 1.f : 0.f;
        const float m4 = (e + 4 < dmain) ? 1.f : 0.f;
        const float m5 = (e + 5 < dmain) ? 1.f : 0.f;
        const float m6 = (e + 6 < dmain) ? 1.f : 0.f;
        const float m7 = (e + 7 < dmain) ? 1.f : 0.f;
        const int t0 = __shfl(tl, e);
        const int t1 = __shfl(tl, j1);
        const int t2 = __shfl(tl, j2);
        const int t3 = __shfl(tl, j3);
        const int t4 = __shfl(tl, j4);
        const int t5 = __shfl(tl, j5);
        const int t6 = __shfl(tl, j6);
        const int t7 = __shfl(tl, j7);
        // 8 independent 256B row loads issue back-to-back
        const __hip_bfloat162 T0 = SP[(long)t0 * 64 + lane];
        const __hip_bfloat162 T1 = SP[(long)t1 * 64 + lane];
        const __hip_bfloat162 T2 = SP[(long)t2 * 64 + lane];
        const __hip_bfloat162 T3 = SP[(long)t3 * 64 + lane];
        const __hip_bfloat162 T4 = SP[(long)t4 * 64 + lane];
        const __hip_bfloat162 T5 = SP[(long)t5 * 64 + lane];
        const __hip_bfloat162 T6 = SP[(long)t6 * 64 + lane];
        const __hip_bfloat162 T7 = SP[(long)t7 * 64 + lane];
        fnuv += (float)((t0 & 1) ^ 1) + m1 * (float)((t1 & 1) ^ 1)
              + m2 * (float)((t2 & 1) ^ 1) + m3 * (float)((t3 & 1) ^ 1)
              + m4 * (float)((t4 & 1) ^ 1) + m5 * (float)((t5 & 1) ^ 1)
              + m6 * (float)((t6 & 1) ^ 1) + m7 * (float)((t7 & 1) ^ 1);
        a0 += __bfloat162float(T0.x) + m1 * __bfloat162float(T1.x)
            + m2 * __bfloat162float(T2.x) + m3 * __bfloat162float(T3.x)
            + m4 * __bfloat162float(T4.x) + m5 * __bfloat162float(T5.x)
            + m6 * __bfloat162float(T6.x) + m7 * __bfloat162float(T7.x);
        a1 += __bfloat162float(T0.y) + m1 * __bfloat162float(T1.y)
            + m2 * __bfloat162float(T2.y) + m3 * __bfloat162float(T3.y)
            + m4 * __bfloat162float(T4.y) + m5 * __bfloat162float(T5.y)
            + m6 * __bfloat162float(T6.y) + m7 * __bfloat162float(T7.y);
    }
    // pathological overflow (deg > 64): serial fallback, essentially never taken
    for (int e2 = start + 64; e2 < start + degc; ++e2) {
        const int t = entries[e2];
        const __hip_bfloat162 T = SP[(long)t * 64 + lane];
        fnuv += (float)((t & 1) ^ 1);
        a0 += __bfloat162float(T.x);
        a1 += __bfloat162float(T.y);
    }

    const float self = 1.0f - WMED * fnuv;
    a0 = fmaf(self, xs0, a0);
    a1 = fmaf(self, xs1, a1);
    float2 o;
    o.x = fmaxf(a0 * din, 0.0f);
    o.y = fmaxf(a1 * din, 0.0f);
    *(float2*)(out + (long)i * 128 + lane * 2) = o;
}

extern "C" void kernel_launch(void* const* d_in, const int* in_sizes, int n_in,
                              void* d_out, int out_size, void* d_ws, size_t ws_size,
                              hipStream_t stream) {
    const float* X      = (const float*)d_in[0];   // [N,128]
    const int*   vertex = (const int*)d_in[1];     // [M*8]
    // d_in[2] = edges (repeat(arange(M),8)) -- unused
    const float* W      = (const float*)d_in[3];   // [128,128]
    const float* bias   = (const float*)d_in[4];   // [128]
    float* out = (float*)d_out;                    // [N,128]

    // workspace: Y[N*128] f32 | Ybf[N*128] bf16 | SP[2M*128] bf16 | deg[N] |
    //            uvpos[M] | cnt[N] | rowptr[N+1] | fill[N] | gcount |
    //            entries | Wg (pre-split W frags, 64 KB, 16B-aligned)
    float* Y              = (float*)d_ws;
    __hip_bfloat16* Ybf   = (__hip_bfloat16*)(Y + (long)NV * 128);
    __hip_bfloat162* SP   = (__hip_bfloat162*)(Ybf + (long)NV * 128);
    float* deg            = (float*)((__hip_bfloat16*)SP + (long)2 * ME * 128);
    int*   uvpos          = (int*)(deg + NV);
    int*   cnt            = uvpos + ME;
    int*   rowptr         = cnt + NV;
    int*   fill           = rowptr + NV + 1;
    int*   gcount         = fill + NV;
    int*   entries        = gcount + 1;
    char*  pW             = (char*)(entries + NINC);
    uint4* Wg             = (uint4*)(((uintptr_t)pW + 15) & ~(uintptr_t)15);

    k_winit<<<NBLK, 256, 0, stream>>>(W, (short*)Wg, cnt, deg, gcount);
    k_gemm <<<NRBG * 2, 256, 0, stream>>>(X, Wg, bias, Y, Ybf);
    k_edge <<<ME / 4, 256, 0, stream>>>(Y, vertex, uvpos, cnt, deg);
    k_scan <<<NBLK, 256, 0, stream>>>(cnt, gcount, rowptr, fill);
    k_fill <<<(NINC + 255) / 256, 256, 0, stream>>>(vertex, uvpos, fill, entries);
    k_sp   <<<ME / 4, 256, 0, stream>>>(Ybf, vertex, uvpos, deg, SP);
    k_gather<<<NV / 4, 256, 0, stream>>>(Y, deg, rowptr, cnt, entries, SP, out);
}

// Round 13
// 241.394 us; speedup vs baseline: 1.2255x; 1.0325x over previous
//
#include <hip/hip_runtime.h>
#include <hip/hip_bf16.h>

// Problem constants (HyperGCNConv: N=100000, M=50000, K=8, DIN=DOUT=128)
#define NV 100000
#define ME 50000
#define NINC (ME * 8)                     // 400000 incidences
#define NBLK ((NV + 255) / 256)           // 391 scan blocks
#define NRBG ((NV + 127) / 128)           // 782 gemm row-blocks (128 rows each)
constexpr float WMED = 1.0f / 13.0f;      // 1/(2K-3), K=8

typedef __attribute__((ext_vector_type(8))) short bf16x8;   // MFMA A/B frag
typedef __attribute__((ext_vector_type(4))) float f32x4;    // MFMA C/D frag

static __device__ inline void cvt_split8(const float4& a, const float4& b,
                                         bf16x8& hi, bf16x8& lo) {
    const float v[8] = {a.x, a.y, a.z, a.w, b.x, b.y, b.z, b.w};
    #pragma unroll
    for (int j = 0; j < 8; ++j) {
        __hip_bfloat16 h = __float2bfloat16(v[j]);
        const float hf = __bfloat162float(h);
        __hip_bfloat16 l = __float2bfloat16(v[j] - hf);
        union { __hip_bfloat16 b; short s; } uh{h}, ul{l};
        hi[j] = uh.s;
        lo[j] = ul.s;
    }
}

// ---------------- K0: one-off W split + workspace init (merged R11) --------
// Wg frag index = mat*2048 + cb*1024 + (s*4+gp)*64 + (qq*16 + m); 16B frags.
// Grid NBLK: all threads init cnt/deg; first 16384 also split W.
__global__ __launch_bounds__(256) void k_winit(const float* __restrict__ W,
                                               short* __restrict__ Wg,
                                               int* __restrict__ cnt,
                                               float* __restrict__ deg,
                                               int* __restrict__ gcount) {
    const int i = blockIdx.x * 256 + threadIdx.x;
    if (i < NV) { cnt[i] = 0; deg[i] = 1.0f; }
    if (i == 0) gcount[0] = 0;
    if (i < 16384) {
        const int k = i >> 7;          // row 0..127
        const int c = i & 127;         // col 0..127
        const float w = W[i];
        __hip_bfloat16 h = __float2bfloat16(w);
        const float hf = __bfloat162float(h);
        __hip_bfloat16 l = __float2bfloat16(w - hf);
        const int cb = c >> 6, gp = (c >> 4) & 3, m = c & 15;
        const int s = k >> 5, qq = (k >> 3) & 3, j = k & 7;
        const int base = cb * 1024 + (s * 4 + gp) * 64 + qq * 16 + m;
        union { __hip_bfloat16 b; short s; } uh{h}, ul{l};
        Wg[(long)base * 8 + j] = uh.s;                    // mat 0 (Wh)
        Wg[(long)(2048 + base) * 8 + j] = ul.s;           // mat 1 (Wl)
    }
}

// ---------------- K1: Y = X @ W + b via split-bf16 MFMA ----------------
// R6: LDS-FREE. Wg (64KB) stays hot in each XCD's L2; B-frags are read
// directly (16B/lane coalesced, L2 latency hidden under MFMAs). No staging,
// no barrier -> waves fully async. 2-stage A prefetch. g-innermost epilogue.
// Plateau-verified ~44-46us across LDS/no-LDS/hoist variants; leave alone.
__global__ __launch_bounds__(256, 4) void k_gemm(const float* __restrict__ X,
                                                 const uint4* __restrict__ Wg,
                                                 const float* __restrict__ bias,
                                                 float* __restrict__ Y,
                                                 __hip_bfloat16* __restrict__ Ybf) {
    const int t = threadIdx.x;
    const int wv = t >> 6;         // wave 0..3 -> rows 32wv..32wv+31
    const int L  = t & 63;
    const int m  = L & 15;         // A row sel / B,C col sel
    const int q  = L >> 4;         // k-quad / C row-quad

    const int rb = blockIdx.x >> 1;       // row block (128 rows)
    const int cb = blockIdx.x & 1;        // col block (64 cols)

    const int row_base = rb * 128 + wv * 32;
    int r0 = row_base + m;      if (r0 > NV - 1) r0 = NV - 1;
    int r1 = row_base + 16 + m; if (r1 > NV - 1) r1 = NV - 1;
    const float* p0 = X + (long)r0 * 128 + q * 8;
    const float* p1 = X + (long)r1 * 128 + q * 8;

    const bf16x8* Whf = (const bf16x8*)Wg + cb * 1024;          // hi frags
    const bf16x8* Wlf = (const bf16x8*)Wg + 2048 + cb * 1024;   // lo frags

    f32x4 acc[2][4];
    #pragma unroll
    for (int tt = 0; tt < 2; ++tt)
        #pragma unroll
        for (int g = 0; g < 4; ++g)
            acc[tt][g] = (f32x4){0.f, 0.f, 0.f, 0.f};

    // 2-stage A pipeline: prefetch s+1 while computing s
    float4 Ac0 = *(const float4*)(p0);
    float4 Ac1 = *(const float4*)(p0 + 4);
    float4 Ac2 = *(const float4*)(p1);
    float4 Ac3 = *(const float4*)(p1 + 4);

    #pragma unroll
    for (int s = 0; s < 4; ++s) {
        float4 An0, An1, An2, An3;
        if (s < 3) {
            An0 = *(const float4*)(p0 + (s + 1) * 32);
            An1 = *(const float4*)(p0 + (s + 1) * 32 + 4);
            An2 = *(const float4*)(p1 + (s + 1) * 32);
            An3 = *(const float4*)(p1 + (s + 1) * 32 + 4);
        }
        bf16x8 ah0, al0, ah1, al1;
        cvt_split8(Ac0, Ac1, ah0, al0);
        cvt_split8(Ac2, Ac3, ah1, al1);
        #pragma unroll
        for (int g = 0; g < 4; ++g) {
            const bf16x8 bh = Whf[(s * 4 + g) * 64 + L];
            const bf16x8 bl = Wlf[(s * 4 + g) * 64 + L];
            acc[0][g] = __builtin_amdgcn_mfma_f32_16x16x32_bf16(ah0, bh, acc[0][g], 0, 0, 0);
            acc[0][g] = __builtin_amdgcn_mfma_f32_16x16x32_bf16(ah0, bl, acc[0][g], 0, 0, 0);
            acc[0][g] = __builtin_amdgcn_mfma_f32_16x16x32_bf16(al0, bh, acc[0][g], 0, 0, 0);
            acc[1][g] = __builtin_amdgcn_mfma_f32_16x16x32_bf16(ah1, bh, acc[1][g], 0, 0, 0);
            acc[1][g] = __builtin_amdgcn_mfma_f32_16x16x32_bf16(ah1, bl, acc[1][g], 0, 0, 0);
            acc[1][g] = __builtin_amdgcn_mfma_f32_16x16x32_bf16(al1, bh, acc[1][g], 0, 0, 0);
        }
        if (s < 3) { Ac0 = An0; Ac1 = An1; Ac2 = An2; Ac3 = An3; }
    }

    // bias per col-group, hoisted
    float bc[4];
    #pragma unroll
    for (int g = 0; g < 4; ++g) bc[g] = bias[cb * 64 + g * 16 + m];

    // epilogue: C layout col=lane&15, row=quad*4+reg; g INNERMOST
    #pragma unroll
    for (int tt = 0; tt < 2; ++tt) {
        #pragma unroll
        for (int r = 0; r < 4; ++r) {
            const int row = row_base + tt * 16 + q * 4 + r;
            float vg[4], vn[4];
            #pragma unroll
            for (int g = 0; g < 4; ++g) {
                vg[g] = acc[tt][g][r] + bc[g];
                vn[g] = __shfl_xor(vg[g], 1);   // neighbor col (lane pair)
            }
            if (row < NV) {
                #pragma unroll
                for (int g = 0; g < 4; ++g)
                    Y[(long)row * 128 + cb * 64 + g * 16 + m] = vg[g];
                if ((L & 1) == 0) {
                    #pragma unroll
                    for (int g = 0; g < 4; ++g) {
                        __hip_bfloat162 h2;
                        h2.x = __float2bfloat16(vg[g]);
                        h2.y = __float2bfloat16(vn[g]);
                        *(__hip_bfloat162*)(Ybf + (long)row * 128 + cb * 64 + g * 16 + m) = h2;
                    }
                }
            }
        }
    }
}

// ---------------- K2: per-hyperedge argmax pair (uvpos only) ----------------
// R10 structure kept: random-512B-gather bound (~2.2TB/s fabric, FETCH 93MB,
// floor ~42us -- implementation-insensitive, verified across 4 variants).
// Fused CSR histogram (R10) + fused deg atomics (R12) ride under the gather.
__global__ __launch_bounds__(256) void k_edge(const float* __restrict__ Y,
                                              const int* __restrict__ vertex,
                                              int* __restrict__ uvpos,
                                              int* __restrict__ cnt,
                                              float* __restrict__ deg) {
    __shared__ float sF[4][8 * 132];
    const int wid = threadIdx.x >> 6;
    const int lane = threadIdx.x & 63;
    const int m = blockIdx.x * 4 + wid;
    float* F = sF[wid];

    int verts[8];
    #pragma unroll
    for (int p = 0; p < 8; ++p) verts[p] = vertex[m * 8 + p];

    // fused histogram: one atomic per incidence, hidden under the row gather
    if (lane < 8) atomicAdd(cnt + vertex[m * 8 + lane], 1);

    #pragma unroll
    for (int p = 0; p < 8; ++p) {
        const float2 v = *(const float2*)(Y + (long)verts[p] * 128 + lane * 2);
        *(float2*)(F + p * 132 + lane * 2) = v;
    }
    __syncthreads();

    const int k = lane >> 3, l = lane & 7;
    float acc = 0.0f;
    const float4* ra = (const float4*)(F + k * 132);
    const float4* rb = (const float4*)(F + l * 132);
    #pragma unroll
    for (int d4 = 0; d4 < 32; ++d4) {
        const float4 a = ra[d4], b = rb[d4];
        acc = fmaf(a.x, b.x, acc);
        acc = fmaf(a.y, b.y, acc);
        acc = fmaf(a.z, b.z, acc);
        acc = fmaf(a.w, b.w, acc);
    }
    const float sqk = __shfl(acc, k * 9);
    const float sql = __shfl(acc, l * 9);
    float v = sqk + sql - 2.0f * acc;
    int idx = lane;
    #pragma unroll
    for (int off = 32; off >= 1; off >>= 1) {
        const float ov = __shfl_xor(v, off);
        const int oi = __shfl_xor(idx, off);
        if (ov > v || (ov == v && oi < idx)) { v = ov; idx = oi; }
    }
    if (lane == 0) uvpos[m] = idx;

    // fused degree: role by POSITION (matches ref's med mask semantics)
    if (lane < 8) {
        const int ui = idx >> 3, vi = idx & 7;
        const float w = (lane == ui || lane == vi) ? (7.0f * WMED) : (2.0f * WMED);
        atomicAdd(deg + vertex[m * 8 + lane], w);
    }
}

// ---------------- CSR build: single-pass scan (R12, merged scan1+scan3) ----
// Block-local inclusive scan; block base from an atomic global cursor.
// rowptr is non-monotonic across blocks (arrival order) but each vertex's
// range is exclusive and valid. R13: rowptr doubles as the fill cursor --
// k_sp's atomics advance it to start+cnt; k_gather recovers start via
// rowptr[i] - cnt[i]. The separate fill array is gone.
__global__ __launch_bounds__(256) void k_scan(const int* __restrict__ cnt,
                                              int* __restrict__ gcount,
                                              int* __restrict__ rowptr) {
    __shared__ int s[256];
    __shared__ int base_s;
    const int t = threadIdx.x;
    const int i = blockIdx.x * 256 + t;
    const int v = (i < NV) ? cnt[i] : 0;
    s[t] = v;
    __syncthreads();
    #pragma unroll
    for (int off = 1; off < 256; off <<= 1) {
        const int add = (t >= off) ? s[t - off] : 0;
        __syncthreads();
        s[t] += add;
        __syncthreads();
    }
    if (t == 255) base_s = atomicAdd(gcount, s[255]);
    __syncthreads();
    if (i < NV) rowptr[i] = base_s + s[t] - v;
}

// ---------------- K4: per-edge w*S,w*P rows + fused entry fill (R13) ------
// Lanes 0..7 write this edge's 8 CSR entries (atomic cursor on rowptr),
// hidden under the same Ybf random-gather latency (R10/R12 precedent).
// k_fill is deleted.
__global__ __launch_bounds__(256) void k_sp(const __hip_bfloat16* __restrict__ Ybf,
                                            const int* __restrict__ vertex,
                                            const int* __restrict__ uvpos,
                                            const float* __restrict__ deg,
                                            int* __restrict__ rowptr,
                                            int* __restrict__ entries,
                                            __hip_bfloat162* __restrict__ SP) {
    const int wid = threadIdx.x >> 6;
    const int lane = threadIdx.x & 63;
    const int m = blockIdx.x * 4 + wid;

    const int idx = uvpos[m];
    const int ui = idx >> 3, vi = idx & 7;

    // fused entry fill: one atomic + one store per incidence
    if (lane < 8) {
        const int vp8 = vertex[m * 8 + lane];
        const int role = (lane == ui || lane == vi) ? 0 : 1;
        const int slot = atomicAdd(rowptr + vp8, 1);
        entries[slot] = (m << 1) | role;
    }

    float S0 = 0.f, S1 = 0.f, U0 = 0.f, U1 = 0.f, V0 = 0.f, V1 = 0.f;
    #pragma unroll
    for (int p = 0; p < 8; ++p) {
        const int vp = vertex[m * 8 + p];
        const float di = rsqrtf(deg[vp]);
        const __hip_bfloat162 y2 =
            ((const __hip_bfloat162*)(Ybf + (long)vp * 128))[lane];
        const float r0 = __bfloat162float(y2.x) * di;
        const float r1 = __bfloat162float(y2.y) * di;
        S0 += r0; S1 += r1;
        if (p == ui) { U0 = r0; U1 = r1; }
        if (p == vi) { V0 = r0; V1 = r1; }
    }
    __hip_bfloat162 s2, p2;
    s2.x = __float2bfloat16(WMED * S0);
    s2.y = __float2bfloat16(WMED * S1);
    p2.x = __float2bfloat16(WMED * (U0 + V0));
    p2.y = __float2bfloat16(WMED * (U1 + V1));
    SP[(long)(2 * m) * 64 + lane] = s2;        // S row
    SP[(long)(2 * m + 1) * 64 + lane] = p2;    // P row
}

// ---------------- K5: per-vertex gather: one bf16 row per incidence --------
// R11: 8-wide chunks (one round covers deg<=8, ~98% of vertices).
// R13: start recovered as rowptr[i]-cnt[i] (rowptr was consumed as cursor).
__global__ __launch_bounds__(256) void k_gather(const float* __restrict__ Y,
                                                const float* __restrict__ deg,
                                                const int* __restrict__ rowptr,
                                                const int* __restrict__ cnt,
                                                const int* __restrict__ entries,
                                                const __hip_bfloat162* __restrict__ SP,
                                                float* __restrict__ out) {
    const int wid = threadIdx.x >> 6;
    const int lane = threadIdx.x & 63;
    const int i = blockIdx.x * 4 + wid;

    const int degc = cnt[i];
    const int start = rowptr[i] - degc;   // cursor ended at start+cnt
    // one coalesced load grabs all entries of this row
    const int tl = (lane < degc) ? entries[start + lane] : 0;

    const float din = rsqrtf(deg[i]);
    const float2 y = *(const float2*)(Y + (long)i * 128 + lane * 2);
    const float xs0 = y.x * din;
    const float xs1 = y.y * din;

    float a0 = 0.f, a1 = 0.f;
    float fnuv = 0.f;
    const int dmain = (degc < 64) ? degc : 64;

    for (int e = 0; e < dmain; e += 8) {
        const int j1 = (e + 1 < dmain) ? e + 1 : e;
        const int j2 = (e + 2 < dmain) ? e + 2 : e;
        const int j3 = (e + 3 < dmain) ? e + 3 : e;
        const int j4 = (e + 4 < dmain) ? e + 4 : e;
        const int j5 = (e + 5 < dmain) ? e + 5 : e;
        const int j6 = (e + 6 < dmain) ? e + 6 : e;
        const int j7 = (e + 7 < dmain) ? e + 7 : e;
        const float m1 = (e + 1 < dmain) ? 1.f : 0.f;
        const float m2 = (e + 2 < dmain) ? 1.f : 0.f;
        const float m3 = (e + 3 < dmain) ? 1.f : 0.f;
        const float m4 = (e + 4 < dmain) ? 1.f : 0.f;
        const float m5 = (e + 5 < dmain) ? 1.f : 0.f;
        const float m6 = (e + 6 < dmain) ? 1.f : 0.f;
        const float m7 = (e + 7 < dmain) ? 1.f : 0.f;
        const int t0 = __shfl(tl, e);
        const int t1 = __shfl(tl, j1);
        const int t2 = __shfl(tl, j2);
        const int t3 = __shfl(tl, j3);
        const int t4 = __shfl(tl, j4);
        const int t5 = __shfl(tl, j5);
        const int t6 = __shfl(tl, j6);
        const int t7 = __shfl(tl, j7);
        // 8 independent 256B row loads issue back-to-back
        const __hip_bfloat162 T0 = SP[(long)t0 * 64 + lane];
        const __hip_bfloat162 T1 = SP[(long)t1 * 64 + lane];
        const __hip_bfloat162 T2 = SP[(long)t2 * 64 + lane];
        const __hip_bfloat162 T3 = SP[(long)t3 * 64 + lane];
        const __hip_bfloat162 T4 = SP[(long)t4 * 64 + lane];
        const __hip_bfloat162 T5 = SP[(long)t5 * 64 + lane];
        const __hip_bfloat162 T6 = SP[(long)t6 * 64 + lane];
        const __hip_bfloat162 T7 = SP[(long)t7 * 64 + lane];
        fnuv += (float)((t0 & 1) ^ 1) + m1 * (float)((t1 & 1) ^ 1)
              + m2 * (float)((t2 & 1) ^ 1) + m3 * (float)((t3 & 1) ^ 1)
              + m4 * (float)((t4 & 1) ^ 1) + m5 * (float)((t5 & 1) ^ 1)
              + m6 * (float)((t6 & 1) ^ 1) + m7 * (float)((t7 & 1) ^ 1);
        a0 += __bfloat162float(T0.x) + m1 * __bfloat162float(T1.x)
            + m2 * __bfloat162float(T2.x) + m3 * __bfloat162float(T3.x)
            + m4 * __bfloat162float(T4.x) + m5 * __bfloat162float(T5.x)
            + m6 * __bfloat162float(T6.x) + m7 * __bfloat162float(T7.x);
        a1 += __bfloat162float(T0.y) + m1 * __bfloat162float(T1.y)
            + m2 * __bfloat162float(T2.y) + m3 * __bfloat162float(T3.y)
            + m4 * __bfloat162float(T4.y) + m5 * __bfloat162float(T5.y)
            + m6 * __bfloat162float(T6.y) + m7 * __bfloat162float(T7.y);
    }
    // pathological overflow (deg > 64): serial fallback, essentially never taken
    for (int e2 = start + 64; e2 < start + degc; ++e2) {
        const int t = entries[e2];
        const __hip_bfloat162 T = SP[(long)t * 64 + lane];
        fnuv += (float)((t & 1) ^ 1);
        a0 += __bfloat162float(T.x);
        a1 += __bfloat162float(T.y);
    }

    const float self = 1.0f - WMED * fnuv;
    a0 = fmaf(self, xs0, a0);
    a1 = fmaf(self, xs1, a1);
    float2 o;
    o.x = fmaxf(a0 * din, 0.0f);
    o.y = fmaxf(a1 * din, 0.0f);
    *(float2*)(out + (long)i * 128 + lane * 2) = o;
}

extern "C" void kernel_launch(void* const* d_in, const int* in_sizes, int n_in,
                              void* d_out, int out_size, void* d_ws, size_t ws_size,
                              hipStream_t stream) {
    const float* X      = (const float*)d_in[0];   // [N,128]
    const int*   vertex = (const int*)d_in[1];     // [M*8]
    // d_in[2] = edges (repeat(arange(M),8)) -- unused
    const float* W      = (const float*)d_in[3];   // [128,128]
    const float* bias   = (const float*)d_in[4];   // [128]
    float* out = (float*)d_out;                    // [N,128]

    // workspace: Y[N*128] f32 | Ybf[N*128] bf16 | SP[2M*128] bf16 | deg[N] |
    //            uvpos[M] | cnt[N] | rowptr[N] | gcount |
    //            entries | Wg (pre-split W frags, 64 KB, 16B-aligned)
    float* Y              = (float*)d_ws;
    __hip_bfloat16* Ybf   = (__hip_bfloat16*)(Y + (long)NV * 128);
    __hip_bfloat162* SP   = (__hip_bfloat162*)(Ybf + (long)NV * 128);
    float* deg            = (float*)((__hip_bfloat16*)SP + (long)2 * ME * 128);
    int*   uvpos          = (int*)(deg + NV);
    int*   cnt            = uvpos + ME;
    int*   rowptr         = cnt + NV;
    int*   gcount         = rowptr + NV;
    int*   entries        = gcount + 1;
    char*  pW             = (char*)(entries + NINC);
    uint4* Wg             = (uint4*)(((uintptr_t)pW + 15) & ~(uintptr_t)15);

    k_winit<<<NBLK, 256, 0, stream>>>(W, (short*)Wg, cnt, deg, gcount);
    k_gemm <<<NRBG * 2, 256, 0, stream>>>(X, Wg, bias, Y, Ybf);
    k_edge <<<ME / 4, 256, 0, stream>>>(Y, vertex, uvpos, cnt, deg);
    k_scan <<<NBLK, 256, 0, stream>>>(cnt, gcount, rowptr);
    k_sp   <<<ME / 4, 256, 0, stream>>>(Ybf, vertex, uvpos, deg, rowptr, entries, SP);
    k_gather<<<NV / 4, 256, 0, stream>>>(Y, deg, rowptr, cnt, entries, SP, out);
}